// Round 1
// baseline (1305.469 us; speedup 1.0000x reference)
//
#include <hip/hip_runtime.h>

#define N_NODES 50000
#define N_EDGES 800000
#define N_GRAPHS 64
#define F_IN 128
#define F_HID 64
#define N_HEADS 4
#define N_CLASSES 10
#define NEG_SLOPE 0.2f
// 1/sqrt(1 + 1e-5), BN eval-mode scale
#define BN_RSQ 0.9999950000374997f

__device__ __forceinline__ float lrelu(float v) { return v > 0.0f ? v : NEG_SLOPE * v; }

// ---------------- CSR build (per call; edge list is restored every call) ----------------
__global__ void k_deg(const int* __restrict__ ei, int* __restrict__ deg) {
    int e = blockIdx.x * blockDim.x + threadIdx.x;
    if (e < N_EDGES) atomicAdd(&deg[ei[N_EDGES + e]], 1);
}

__global__ void k_scan(const int* __restrict__ deg, int* __restrict__ offs) {
    __shared__ int sbuf[1024];
    const int t = threadIdx.x;
    const int CH = (N_NODES + 1023) / 1024;  // 49
    int base = t * CH;
    int s = 0;
    for (int i = 0; i < CH; ++i) { int idx = base + i; if (idx < N_NODES) s += deg[idx]; }
    sbuf[t] = s;
    __syncthreads();
    for (int off = 1; off < 1024; off <<= 1) {
        int v = (t >= off) ? sbuf[t - off] : 0;
        __syncthreads();
        sbuf[t] += v;
        __syncthreads();
    }
    int run = (t == 0) ? 0 : sbuf[t - 1];
    for (int i = 0; i < CH; ++i) {
        int idx = base + i;
        if (idx < N_NODES) { offs[idx] = run; run += deg[idx]; }
    }
}

__global__ void k_fill(const int* __restrict__ ei, const int* __restrict__ offs,
                       int* __restrict__ cur, int* __restrict__ csr_src) {
    int e = blockIdx.x * blockDim.x + threadIdx.x;
    if (e < N_EDGES) {
        int d = ei[N_EDGES + e];
        int pos = offs[d] + atomicAdd(&cur[d], 1);
        csr_src[pos] = ei[e];
    }
}

// ---------------- GEMM: out[N,J] = X[N,K] @ W[K,J] ----------------
// 32 rows per block, 256 threads; 256/J groups each handling 32*J/256 rows.
template <int K, int J>
__global__ __launch_bounds__(256) void k_gemm(const float* __restrict__ X,
                                              const float* __restrict__ W,
                                              float* __restrict__ out, int Nrows) {
    constexpr int TM = 32;
    constexpr int GROUPS = 256 / J;  // 1 (J=256) or 4 (J=64)
    constexpr int MPG = TM / GROUPS; // 32 or 8
    constexpr int LDK = K + 4;       // pad keeps float4 alignment, breaks bank stride
    __shared__ float xs[TM * LDK];
    const int tid = threadIdx.x;
    const int n0 = blockIdx.x * TM;
    for (int i = tid; i < TM * K; i += 256) {
        int r = i / K, c = i % K;  // K is a power of two -> shifts
        int row = n0 + r;
        xs[r * LDK + c] = (row < Nrows) ? X[row * K + c] : 0.0f;
    }
    __syncthreads();
    const int col = tid % J;
    const int grp = tid / J;
    float acc[MPG];
#pragma unroll
    for (int m = 0; m < MPG; ++m) acc[m] = 0.0f;
    for (int k = 0; k < K; k += 4) {
        const float w0 = W[(k + 0) * J + col];
        const float w1 = W[(k + 1) * J + col];
        const float w2 = W[(k + 2) * J + col];
        const float w3 = W[(k + 3) * J + col];
#pragma unroll
        for (int m = 0; m < MPG; ++m) {
            const float4 x4 = *(const float4*)&xs[(grp * MPG + m) * LDK + k];
            acc[m] = fmaf(x4.x, w0, fmaf(x4.y, w1, fmaf(x4.z, w2, fmaf(x4.w, w3, acc[m]))));
        }
    }
#pragma unroll
    for (int m = 0; m < MPG; ++m) {
        int row = n0 + grp * MPG + m;
        if (row < Nrows) out[row * J + col] = acc[m];
    }
}

// ---------------- attention score dots ----------------
// layer 1: H=4 heads x 64 feats. one wave per node; lane covers feats 4l..4l+3 (head = l>>4)
__global__ void k_dots4(const float* __restrict__ xW, const float* __restrict__ asrc,
                        const float* __restrict__ adst, float* __restrict__ es,
                        float* __restrict__ ed) {
    int w = (blockIdx.x * blockDim.x + threadIdx.x) >> 6;
    int lane = threadIdx.x & 63;
    if (w >= N_NODES) return;
    const float4 xv = *(const float4*)&xW[w * 256 + lane * 4];
    const float4 as = *(const float4*)&asrc[lane * 4];
    const float4 ad = *(const float4*)&adst[lane * 4];
    float ss = xv.x * as.x + xv.y * as.y + xv.z * as.z + xv.w * as.w;
    float dd = xv.x * ad.x + xv.y * ad.y + xv.z * ad.z + xv.w * ad.w;
    for (int off = 1; off < 16; off <<= 1) {
        ss += __shfl_xor(ss, off);
        dd += __shfl_xor(dd, off);
    }
    if ((lane & 15) == 0) {
        es[w * 4 + (lane >> 4)] = ss;
        ed[w * 4 + (lane >> 4)] = dd;
    }
}

// layers 2-4: H=1, 64 feats. one wave per node.
__global__ void k_dots1(const float* __restrict__ xW, const float* __restrict__ asrc,
                        const float* __restrict__ adst, float* __restrict__ es,
                        float* __restrict__ ed) {
    int w = (blockIdx.x * blockDim.x + threadIdx.x) >> 6;
    int lane = threadIdx.x & 63;
    if (w >= N_NODES) return;
    float xv = xW[w * 64 + lane];
    float ss = xv * asrc[lane];
    float dd = xv * adst[lane];
    for (int off = 1; off < 64; off <<= 1) {
        ss += __shfl_xor(ss, off);
        dd += __shfl_xor(dd, off);
    }
    if (lane == 0) { es[w] = ss; ed[w] = dd; }
}

// ---------------- GAT layer 1: H=4, F=64, out 256, + bias + relu ----------------
__global__ __launch_bounds__(256) void k_gat1(
    const float* __restrict__ xW, const float* __restrict__ es, const float* __restrict__ ed,
    const int* __restrict__ offs, const int* __restrict__ deg, const int* __restrict__ csr,
    const float* __restrict__ bias, float* __restrict__ out) {
    const int n = (blockIdx.x * blockDim.x + threadIdx.x) >> 6;
    const int lane = threadIdx.x & 63;
    if (n >= N_NODES) return;
    const int off = offs[n];
    const int dg = deg[n];
    const float4 edv = *(const float4*)&ed[n * 4];
    const int head = lane >> 4;

    // pass 1: per-head max of leaky(es[src]+ed[n])
    float m0 = -3.0e38f, m1 = -3.0e38f, m2 = -3.0e38f, m3 = -3.0e38f;
    for (int i = lane; i < dg; i += 64) {
        int s = csr[off + i];
        const float4 ev = *(const float4*)&es[s * 4];
        m0 = fmaxf(m0, lrelu(ev.x + edv.x));
        m1 = fmaxf(m1, lrelu(ev.y + edv.y));
        m2 = fmaxf(m2, lrelu(ev.z + edv.z));
        m3 = fmaxf(m3, lrelu(ev.w + edv.w));
    }
    for (int o = 1; o < 64; o <<= 1) {
        m0 = fmaxf(m0, __shfl_xor(m0, o));
        m1 = fmaxf(m1, __shfl_xor(m1, o));
        m2 = fmaxf(m2, __shfl_xor(m2, o));
        m3 = fmaxf(m3, __shfl_xor(m3, o));
    }

    // pass 2: acc = sum p * xW[src], dsum = sum p (normalize at the end)
    float4 acc = make_float4(0.f, 0.f, 0.f, 0.f);
    float d0 = 0.f, d1 = 0.f, d2 = 0.f, d3 = 0.f;
    for (int base = 0; base < dg; base += 64) {
        int idx = base + lane;
        int s_l = 0;
        float p0 = 0.f, p1 = 0.f, p2 = 0.f, p3 = 0.f;
        if (idx < dg) {
            s_l = csr[off + idx];
            const float4 ev = *(const float4*)&es[s_l * 4];
            p0 = __expf(lrelu(ev.x + edv.x) - m0);
            p1 = __expf(lrelu(ev.y + edv.y) - m1);
            p2 = __expf(lrelu(ev.z + edv.z) - m2);
            p3 = __expf(lrelu(ev.w + edv.w) - m3);
        }
        d0 += p0; d1 += p1; d2 += p2; d3 += p3;
        const int cnt = min(64, dg - base);
        for (int j = 0; j < cnt; ++j) {
            const int sj = __shfl(s_l, j);
            const float q0 = __shfl(p0, j);
            const float q1 = __shfl(p1, j);
            const float q2 = __shfl(p2, j);
            const float q3 = __shfl(p3, j);
            const float psel = head == 0 ? q0 : head == 1 ? q1 : head == 2 ? q2 : q3;
            const float4 xv = *(const float4*)&xW[sj * 256 + lane * 4];
            acc.x = fmaf(psel, xv.x, acc.x);
            acc.y = fmaf(psel, xv.y, acc.y);
            acc.z = fmaf(psel, xv.z, acc.z);
            acc.w = fmaf(psel, xv.w, acc.w);
        }
    }
    for (int o = 1; o < 64; o <<= 1) {
        d0 += __shfl_xor(d0, o);
        d1 += __shfl_xor(d1, o);
        d2 += __shfl_xor(d2, o);
        d3 += __shfl_xor(d3, o);
    }
    const float dsel = head == 0 ? d0 : head == 1 ? d1 : head == 2 ? d2 : d3;
    const float inv = 1.0f / fmaxf(dsel, 1e-16f);
    const float4 bv = *(const float4*)&bias[lane * 4];
    float4 o4;
    o4.x = fmaxf(fmaf(acc.x, inv, bv.x), 0.f);
    o4.y = fmaxf(fmaf(acc.y, inv, bv.y), 0.f);
    o4.z = fmaxf(fmaf(acc.z, inv, bv.z), 0.f);
    o4.w = fmaxf(fmaf(acc.w, inv, bv.w), 0.f);
    *(float4*)&out[n * 256 + lane * 4] = o4;
}

// ---------------- GAT layers 2-4: H=1, F=64, + bias + BN + relu (+ residual) ----------------
template <bool RES>
__global__ __launch_bounds__(256) void k_gatL(
    const float* __restrict__ xW, const float* __restrict__ es, const float* __restrict__ ed,
    const int* __restrict__ offs, const int* __restrict__ deg, const int* __restrict__ csr,
    const float* __restrict__ bias, const float* __restrict__ gam, const float* __restrict__ bet,
    float* __restrict__ h) {
    const int n = (blockIdx.x * blockDim.x + threadIdx.x) >> 6;
    const int lane = threadIdx.x & 63;
    if (n >= N_NODES) return;
    const int off = offs[n];
    const int dg = deg[n];
    const float edn = ed[n];

    float m = -3.0e38f;
    for (int i = lane; i < dg; i += 64) {
        int s = csr[off + i];
        m = fmaxf(m, lrelu(es[s] + edn));
    }
    for (int o = 1; o < 64; o <<= 1) m = fmaxf(m, __shfl_xor(m, o));

    float acc = 0.f, dsum = 0.f;
    for (int base = 0; base < dg; base += 64) {
        int idx = base + lane;
        int s_l = 0;
        float p_l = 0.f;
        if (idx < dg) {
            s_l = csr[off + idx];
            p_l = __expf(lrelu(es[s_l] + edn) - m);
        }
        dsum += p_l;
        const int cnt = min(64, dg - base);
        for (int j = 0; j < cnt; ++j) {
            const int sj = __shfl(s_l, j);
            const float pj = __shfl(p_l, j);
            acc = fmaf(pj, xW[sj * 64 + lane], acc);
        }
    }
    for (int o = 1; o < 64; o <<= 1) dsum += __shfl_xor(dsum, o);

    const float y = acc / fmaxf(dsum, 1e-16f) + bias[lane];
    const float z = fmaxf(fmaf(gam[lane] * y, BN_RSQ, bet[lane]), 0.f);
    h[n * 64 + lane] = RES ? h[n * 64 + lane] + z : z;
}

// ---------------- mean pool ----------------
__global__ void k_pool(const float* __restrict__ h, const int* __restrict__ batch,
                       float* __restrict__ pooled, float* __restrict__ cnt) {
    int n = (blockIdx.x * blockDim.x + threadIdx.x) >> 6;
    int lane = threadIdx.x & 63;
    if (n >= N_NODES) return;
    int bg = batch[n];
    atomicAdd(&pooled[bg * 64 + lane], h[n * 64 + lane]);
    if (lane == 0) atomicAdd(&cnt[bg], 1.0f);
}

// ---------------- MLP head, single block ----------------
__global__ __launch_bounds__(256) void k_head(const float* __restrict__ pooled,
                                              const float* __restrict__ cnt,
                                              const float* __restrict__ Wh1,
                                              const float* __restrict__ bh1,
                                              const float* __restrict__ Wh2,
                                              const float* __restrict__ bh2,
                                              float* __restrict__ out) {
    __shared__ float hp[64 * 64];
    __shared__ float t1[64 * 128];
    const int tid = threadIdx.x;
    for (int i = tid; i < 64 * 64; i += 256) {
        int g = i >> 6;
        hp[i] = pooled[i] / fmaxf(cnt[g], 1.0f);
    }
    __syncthreads();
    for (int i = tid; i < 64 * 128; i += 256) {
        int g = i >> 7, j = i & 127;
        float s = bh1[j];
        for (int k = 0; k < 64; ++k) s = fmaf(hp[g * 64 + k], Wh1[k * 128 + j], s);
        t1[i] = fmaxf(s, 0.f);
    }
    __syncthreads();
    for (int i = tid; i < 640; i += 256) {
        int g = i / 10, j = i - g * 10;
        float s = bh2[j];
        for (int k = 0; k < 128; ++k) s = fmaf(t1[g * 128 + k], Wh2[k * 10 + j], s);
        out[i] = s;
    }
}

extern "C" void kernel_launch(void* const* d_in, const int* in_sizes, int n_in,
                              void* d_out, int out_size, void* d_ws, size_t ws_size,
                              hipStream_t stream) {
    const float* x = (const float*)d_in[1];
    const int* ei = (const int*)d_in[2];
    const int* batch = (const int*)d_in[3];
    const float* W1 = (const float*)d_in[4];
    const float* a_src1 = (const float*)d_in[5];
    const float* a_dst1 = (const float*)d_in[6];
    const float* b1 = (const float*)d_in[7];
    const float* W2 = (const float*)d_in[8];
    const float* a_src2 = (const float*)d_in[9];
    const float* a_dst2 = (const float*)d_in[10];
    const float* b2 = (const float*)d_in[11];
    const float* g2 = (const float*)d_in[12];
    const float* be2 = (const float*)d_in[13];
    const float* W3 = (const float*)d_in[14];
    const float* a_src3 = (const float*)d_in[15];
    const float* a_dst3 = (const float*)d_in[16];
    const float* b3 = (const float*)d_in[17];
    const float* g3 = (const float*)d_in[18];
    const float* be3 = (const float*)d_in[19];
    const float* W4 = (const float*)d_in[20];
    const float* a_src4 = (const float*)d_in[21];
    const float* a_dst4 = (const float*)d_in[22];
    const float* b4 = (const float*)d_in[23];
    const float* g4 = (const float*)d_in[24];
    const float* be4 = (const float*)d_in[25];
    const float* Wh1 = (const float*)d_in[26];
    const float* bh1 = (const float*)d_in[27];
    const float* Wh2 = (const float*)d_in[28];
    const float* bh2 = (const float*)d_in[29];
    float* out = (float*)d_out;

    // workspace layout
    char* p = (char*)d_ws;
    auto alloc = [&](size_t bytes) {
        void* r = (void*)p;
        p += (bytes + 255) & ~(size_t)255;
        return r;
    };
    float* bufA = (float*)alloc((size_t)N_NODES * 256 * 4);  // xW1, then xW_l (layers 2-4)
    float* bufB = (float*)alloc((size_t)N_NODES * 256 * 4);  // x1,  then h
    float* es1 = (float*)alloc((size_t)N_NODES * 4 * 4);
    float* ed1 = (float*)alloc((size_t)N_NODES * 4 * 4);
    float* esL = (float*)alloc((size_t)N_NODES * 4);
    float* edL = (float*)alloc((size_t)N_NODES * 4);
    int* offs = (int*)alloc((size_t)N_NODES * 4);
    int* csr = (int*)alloc((size_t)N_EDGES * 4);
    char* z0 = p;  // everything below gets zeroed each call
    int* deg = (int*)alloc((size_t)N_NODES * 4);
    int* cur = (int*)alloc((size_t)N_NODES * 4);
    float* pooled = (float*)alloc((size_t)N_GRAPHS * 64 * 4);
    float* cntb = (float*)alloc((size_t)N_GRAPHS * 4);
    size_t zbytes = (size_t)(p - z0);
    hipMemsetAsync(z0, 0, zbytes, stream);

    const int edgeBlocks = (N_EDGES + 255) / 256;
    const int gemmBlocks = (N_NODES + 31) / 32;
    const int waveBlocks = (N_NODES * 64 + 255) / 256;

    // CSR build
    k_deg<<<edgeBlocks, 256, 0, stream>>>(ei, deg);
    k_scan<<<1, 1024, 0, stream>>>(deg, offs);
    k_fill<<<edgeBlocks, 256, 0, stream>>>(ei, offs, cur, csr);

    // layer 1: GAT(128 -> 4x64, concat) + relu
    k_gemm<128, 256><<<gemmBlocks, 256, 0, stream>>>(x, W1, bufA, N_NODES);
    k_dots4<<<waveBlocks, 256, 0, stream>>>(bufA, a_src1, a_dst1, es1, ed1);
    k_gat1<<<waveBlocks, 256, 0, stream>>>(bufA, es1, ed1, offs, deg, csr, b1, bufB);

    // layer 2: GAT(256 -> 64) + BN + relu
    k_gemm<256, 64><<<gemmBlocks, 256, 0, stream>>>(bufB, W2, bufA, N_NODES);
    k_dots1<<<waveBlocks, 256, 0, stream>>>(bufA, a_src2, a_dst2, esL, edL);
    k_gatL<false><<<waveBlocks, 256, 0, stream>>>(bufA, esL, edL, offs, deg, csr, b2, g2, be2, bufB);

    // layer 3: residual GAT(64 -> 64) + BN + relu
    k_gemm<64, 64><<<gemmBlocks, 256, 0, stream>>>(bufB, W3, bufA, N_NODES);
    k_dots1<<<waveBlocks, 256, 0, stream>>>(bufA, a_src3, a_dst3, esL, edL);
    k_gatL<true><<<waveBlocks, 256, 0, stream>>>(bufA, esL, edL, offs, deg, csr, b3, g3, be3, bufB);

    // layer 4: residual GAT(64 -> 64) + BN + relu
    k_gemm<64, 64><<<gemmBlocks, 256, 0, stream>>>(bufB, W4, bufA, N_NODES);
    k_dots1<<<waveBlocks, 256, 0, stream>>>(bufA, a_src4, a_dst4, esL, edL);
    k_gatL<true><<<waveBlocks, 256, 0, stream>>>(bufA, esL, edL, offs, deg, csr, b4, g4, be4, bufB);

    // pool + head
    k_pool<<<waveBlocks, 256, 0, stream>>>(bufB, batch, pooled, cntb);
    k_head<<<1, 256, 0, stream>>>(pooled, cntb, Wh1, bh1, Wh2, bh2, out);
}

// Round 2
// 949.706 us; speedup vs baseline: 1.3746x; 1.3746x over previous
//
#include <hip/hip_runtime.h>

#define N_NODES 50000
#define N_EDGES 800000
#define N_GRAPHS 64
#define F_IN 128
#define F_HID 64
#define N_HEADS 4
#define N_CLASSES 10
#define NEG_SLOPE 0.2f
// 1/sqrt(1 + 1e-5), BN eval-mode scale
#define BN_RSQ 0.9999950000374997f

__device__ __forceinline__ float lrelu(float v) { return v > 0.0f ? v : NEG_SLOPE * v; }

// ---------------- CSR build (per call; edge list is restored every call) ----------------
__global__ void k_deg(const int* __restrict__ ei, int* __restrict__ deg) {
    int e = blockIdx.x * blockDim.x + threadIdx.x;
    if (e < N_EDGES) atomicAdd(&deg[ei[N_EDGES + e]], 1);
}

__global__ void k_scan(const int* __restrict__ deg, int* __restrict__ offs) {
    __shared__ int sbuf[1024];
    const int t = threadIdx.x;
    const int CH = (N_NODES + 1023) / 1024;  // 49
    int base = t * CH;
    int s = 0;
    for (int i = 0; i < CH; ++i) { int idx = base + i; if (idx < N_NODES) s += deg[idx]; }
    sbuf[t] = s;
    __syncthreads();
    for (int off = 1; off < 1024; off <<= 1) {
        int v = (t >= off) ? sbuf[t - off] : 0;
        __syncthreads();
        sbuf[t] += v;
        __syncthreads();
    }
    int run = (t == 0) ? 0 : sbuf[t - 1];
    for (int i = 0; i < CH; ++i) {
        int idx = base + i;
        if (idx < N_NODES) { offs[idx] = run; run += deg[idx]; }
    }
}

__global__ void k_fill(const int* __restrict__ ei, const int* __restrict__ offs,
                       int* __restrict__ cur, int* __restrict__ csr_src) {
    int e = blockIdx.x * blockDim.x + threadIdx.x;
    if (e < N_EDGES) {
        int d = ei[N_EDGES + e];
        int pos = offs[d] + atomicAdd(&cur[d], 1);
        csr_src[pos] = ei[e];
    }
}

// graph boundaries: batch is sorted, so graph g owns nodes [bounds[g], bounds[g+1])
__global__ void k_bounds(const int* __restrict__ batch, int* __restrict__ bounds) {
    int g = threadIdx.x;
    if (g > N_GRAPHS) return;
    int lo = 0, hi = N_NODES;
    while (lo < hi) {
        int mid = (lo + hi) >> 1;
        if (batch[mid] < g) lo = mid + 1; else hi = mid;
    }
    bounds[g] = lo;
}

// ---------------- GEMM: out[N,J] = X[N,K] @ W[K,J] ----------------
template <int K, int J>
__global__ __launch_bounds__(256) void k_gemm(const float* __restrict__ X,
                                              const float* __restrict__ W,
                                              float* __restrict__ out, int Nrows) {
    constexpr int TM = 32;
    constexpr int GROUPS = 256 / J;  // 1 (J=256) or 4 (J=64)
    constexpr int MPG = TM / GROUPS; // 32 or 8
    constexpr int LDK = K + 4;       // pad keeps float4 alignment, breaks bank stride
    __shared__ float xs[TM * LDK];
    const int tid = threadIdx.x;
    const int n0 = blockIdx.x * TM;
    for (int i = tid; i < TM * K; i += 256) {
        int r = i / K, c = i % K;
        int row = n0 + r;
        xs[r * LDK + c] = (row < Nrows) ? X[row * K + c] : 0.0f;
    }
    __syncthreads();
    const int col = tid % J;
    const int grp = tid / J;
    float acc[MPG];
#pragma unroll
    for (int m = 0; m < MPG; ++m) acc[m] = 0.0f;
    for (int k = 0; k < K; k += 4) {
        const float w0 = W[(k + 0) * J + col];
        const float w1 = W[(k + 1) * J + col];
        const float w2 = W[(k + 2) * J + col];
        const float w3 = W[(k + 3) * J + col];
#pragma unroll
        for (int m = 0; m < MPG; ++m) {
            const float4 x4 = *(const float4*)&xs[(grp * MPG + m) * LDK + k];
            acc[m] = fmaf(x4.x, w0, fmaf(x4.y, w1, fmaf(x4.z, w2, fmaf(x4.w, w3, acc[m]))));
        }
    }
#pragma unroll
    for (int m = 0; m < MPG; ++m) {
        int row = n0 + grp * MPG + m;
        if (row < Nrows) out[row * J + col] = acc[m];
    }
}

// ---------------- attention score dots ----------------
__global__ void k_dots4(const float* __restrict__ xW, const float* __restrict__ asrc,
                        const float* __restrict__ adst, float* __restrict__ es,
                        float* __restrict__ ed) {
    int w = (blockIdx.x * blockDim.x + threadIdx.x) >> 6;
    int lane = threadIdx.x & 63;
    if (w >= N_NODES) return;
    const float4 xv = *(const float4*)&xW[w * 256 + lane * 4];
    const float4 as = *(const float4*)&asrc[lane * 4];
    const float4 ad = *(const float4*)&adst[lane * 4];
    float ss = xv.x * as.x + xv.y * as.y + xv.z * as.z + xv.w * as.w;
    float dd = xv.x * ad.x + xv.y * ad.y + xv.z * ad.z + xv.w * ad.w;
    for (int off = 1; off < 16; off <<= 1) {
        ss += __shfl_xor(ss, off);
        dd += __shfl_xor(dd, off);
    }
    if ((lane & 15) == 0) {
        es[w * 4 + (lane >> 4)] = ss;
        ed[w * 4 + (lane >> 4)] = dd;
    }
}

__global__ void k_dots1(const float* __restrict__ xW, const float* __restrict__ asrc,
                        const float* __restrict__ adst, float* __restrict__ es,
                        float* __restrict__ ed) {
    int w = (blockIdx.x * blockDim.x + threadIdx.x) >> 6;
    int lane = threadIdx.x & 63;
    if (w >= N_NODES) return;
    float xv = xW[w * 64 + lane];
    float ss = xv * asrc[lane];
    float dd = xv * adst[lane];
    for (int off = 1; off < 64; off <<= 1) {
        ss += __shfl_xor(ss, off);
        dd += __shfl_xor(dd, off);
    }
    if (lane == 0) { es[w] = ss; ed[w] = dd; }
}

// ---------------- GAT layer 1: H=4, F=64, out 256, + bias + relu ----------------
__global__ __launch_bounds__(256) void k_gat1(
    const float* __restrict__ xW, const float* __restrict__ es, const float* __restrict__ ed,
    const int* __restrict__ offs, const int* __restrict__ deg, const int* __restrict__ csr,
    const float* __restrict__ bias, float* __restrict__ out) {
    const int n = (blockIdx.x * blockDim.x + threadIdx.x) >> 6;
    const int lane = threadIdx.x & 63;
    if (n >= N_NODES) return;
    const int off = offs[n];
    const int dg = deg[n];
    const float4 edv = *(const float4*)&ed[n * 4];
    const int head = lane >> 4;

    float m0 = -3.0e38f, m1 = -3.0e38f, m2 = -3.0e38f, m3 = -3.0e38f;
    for (int i = lane; i < dg; i += 64) {
        int s = csr[off + i];
        const float4 ev = *(const float4*)&es[s * 4];
        m0 = fmaxf(m0, lrelu(ev.x + edv.x));
        m1 = fmaxf(m1, lrelu(ev.y + edv.y));
        m2 = fmaxf(m2, lrelu(ev.z + edv.z));
        m3 = fmaxf(m3, lrelu(ev.w + edv.w));
    }
    for (int o = 1; o < 64; o <<= 1) {
        m0 = fmaxf(m0, __shfl_xor(m0, o));
        m1 = fmaxf(m1, __shfl_xor(m1, o));
        m2 = fmaxf(m2, __shfl_xor(m2, o));
        m3 = fmaxf(m3, __shfl_xor(m3, o));
    }

    float4 acc = make_float4(0.f, 0.f, 0.f, 0.f);
    float d0 = 0.f, d1 = 0.f, d2 = 0.f, d3 = 0.f;
    for (int base = 0; base < dg; base += 64) {
        int idx = base + lane;
        int s_l = 0;
        float p0 = 0.f, p1 = 0.f, p2 = 0.f, p3 = 0.f;
        if (idx < dg) {
            s_l = csr[off + idx];
            const float4 ev = *(const float4*)&es[s_l * 4];
            p0 = __expf(lrelu(ev.x + edv.x) - m0);
            p1 = __expf(lrelu(ev.y + edv.y) - m1);
            p2 = __expf(lrelu(ev.z + edv.z) - m2);
            p3 = __expf(lrelu(ev.w + edv.w) - m3);
        }
        d0 += p0; d1 += p1; d2 += p2; d3 += p3;
        const int cnt = min(64, dg - base);
        for (int j = 0; j < cnt; ++j) {
            const int sj = __shfl(s_l, j);
            const float q0 = __shfl(p0, j);
            const float q1 = __shfl(p1, j);
            const float q2 = __shfl(p2, j);
            const float q3 = __shfl(p3, j);
            const float psel = head == 0 ? q0 : head == 1 ? q1 : head == 2 ? q2 : q3;
            const float4 xv = *(const float4*)&xW[sj * 256 + lane * 4];
            acc.x = fmaf(psel, xv.x, acc.x);
            acc.y = fmaf(psel, xv.y, acc.y);
            acc.z = fmaf(psel, xv.z, acc.z);
            acc.w = fmaf(psel, xv.w, acc.w);
        }
    }
    for (int o = 1; o < 64; o <<= 1) {
        d0 += __shfl_xor(d0, o);
        d1 += __shfl_xor(d1, o);
        d2 += __shfl_xor(d2, o);
        d3 += __shfl_xor(d3, o);
    }
    const float dsel = head == 0 ? d0 : head == 1 ? d1 : head == 2 ? d2 : d3;
    const float inv = 1.0f / fmaxf(dsel, 1e-16f);
    const float4 bv = *(const float4*)&bias[lane * 4];
    float4 o4;
    o4.x = fmaxf(fmaf(acc.x, inv, bv.x), 0.f);
    o4.y = fmaxf(fmaf(acc.y, inv, bv.y), 0.f);
    o4.z = fmaxf(fmaf(acc.z, inv, bv.z), 0.f);
    o4.w = fmaxf(fmaf(acc.w, inv, bv.w), 0.f);
    *(float4*)&out[n * 256 + lane * 4] = o4;
}

// ---------------- GAT layers 2-4: H=1, F=64, + bias + BN + relu (+ residual) ----------------
template <bool RES>
__global__ __launch_bounds__(256) void k_gatL(
    const float* __restrict__ xW, const float* __restrict__ es, const float* __restrict__ ed,
    const int* __restrict__ offs, const int* __restrict__ deg, const int* __restrict__ csr,
    const float* __restrict__ bias, const float* __restrict__ gam, const float* __restrict__ bet,
    float* __restrict__ h) {
    const int n = (blockIdx.x * blockDim.x + threadIdx.x) >> 6;
    const int lane = threadIdx.x & 63;
    if (n >= N_NODES) return;
    const int off = offs[n];
    const int dg = deg[n];
    const float edn = ed[n];

    float m = -3.0e38f;
    for (int i = lane; i < dg; i += 64) {
        int s = csr[off + i];
        m = fmaxf(m, lrelu(es[s] + edn));
    }
    for (int o = 1; o < 64; o <<= 1) m = fmaxf(m, __shfl_xor(m, o));

    float acc = 0.f, dsum = 0.f;
    for (int base = 0; base < dg; base += 64) {
        int idx = base + lane;
        int s_l = 0;
        float p_l = 0.f;
        if (idx < dg) {
            s_l = csr[off + idx];
            p_l = __expf(lrelu(es[s_l] + edn) - m);
        }
        dsum += p_l;
        const int cnt = min(64, dg - base);
        for (int j = 0; j < cnt; ++j) {
            const int sj = __shfl(s_l, j);
            const float pj = __shfl(p_l, j);
            acc = fmaf(pj, xW[sj * 64 + lane], acc);
        }
    }
    for (int o = 1; o < 64; o <<= 1) dsum += __shfl_xor(dsum, o);

    const float y = acc / fmaxf(dsum, 1e-16f) + bias[lane];
    const float z = fmaxf(fmaf(gam[lane] * y, BN_RSQ, bet[lane]), 0.f);
    h[n * 64 + lane] = RES ? h[n * 64 + lane] + z : z;
}

// ---------------- mean pool: one block per graph, contiguous node range, no atomics ----------------
__global__ __launch_bounds__(256) void k_pool2(const float* __restrict__ h,
                                               const int* __restrict__ bounds,
                                               float* __restrict__ hp) {
    __shared__ float part[4][64];
    const int g = blockIdx.x;
    const int lane = threadIdx.x & 63;
    const int wid = threadIdx.x >> 6;
    const int s = bounds[g], e = bounds[g + 1];
    float acc = 0.f;
    for (int n = s + wid; n < e; n += 4) acc += h[n * 64 + lane];
    part[wid][lane] = acc;
    __syncthreads();
    if (wid == 0) {
        float v = part[0][lane] + part[1][lane] + part[2][lane] + part[3][lane];
        hp[g * 64 + lane] = v / fmaxf((float)(e - s), 1.0f);
    }
}

// ---------------- MLP head, single block (hp already mean-pooled) ----------------
__global__ __launch_bounds__(256) void k_head(const float* __restrict__ hpg,
                                              const float* __restrict__ Wh1,
                                              const float* __restrict__ bh1,
                                              const float* __restrict__ Wh2,
                                              const float* __restrict__ bh2,
                                              float* __restrict__ out) {
    __shared__ float hp[64 * 64];
    __shared__ float t1[64 * 128];
    const int tid = threadIdx.x;
    for (int i = tid; i < 64 * 64; i += 256) hp[i] = hpg[i];
    __syncthreads();
    for (int i = tid; i < 64 * 128; i += 256) {
        int g = i >> 7, j = i & 127;
        float s = bh1[j];
        for (int k = 0; k < 64; ++k) s = fmaf(hp[g * 64 + k], Wh1[k * 128 + j], s);
        t1[i] = fmaxf(s, 0.f);
    }
    __syncthreads();
    for (int i = tid; i < 640; i += 256) {
        int g = i / 10, j = i - g * 10;
        float s = bh2[j];
        for (int k = 0; k < 128; ++k) s = fmaf(t1[g * 128 + k], Wh2[k * 10 + j], s);
        out[i] = s;
    }
}

extern "C" void kernel_launch(void* const* d_in, const int* in_sizes, int n_in,
                              void* d_out, int out_size, void* d_ws, size_t ws_size,
                              hipStream_t stream) {
    const float* x = (const float*)d_in[1];
    const int* ei = (const int*)d_in[2];
    const int* batch = (const int*)d_in[3];
    const float* W1 = (const float*)d_in[4];
    const float* a_src1 = (const float*)d_in[5];
    const float* a_dst1 = (const float*)d_in[6];
    const float* b1 = (const float*)d_in[7];
    const float* W2 = (const float*)d_in[8];
    const float* a_src2 = (const float*)d_in[9];
    const float* a_dst2 = (const float*)d_in[10];
    const float* b2 = (const float*)d_in[11];
    const float* g2 = (const float*)d_in[12];
    const float* be2 = (const float*)d_in[13];
    const float* W3 = (const float*)d_in[14];
    const float* a_src3 = (const float*)d_in[15];
    const float* a_dst3 = (const float*)d_in[16];
    const float* b3 = (const float*)d_in[17];
    const float* g3 = (const float*)d_in[18];
    const float* be3 = (const float*)d_in[19];
    const float* W4 = (const float*)d_in[20];
    const float* a_src4 = (const float*)d_in[21];
    const float* a_dst4 = (const float*)d_in[22];
    const float* b4 = (const float*)d_in[23];
    const float* g4 = (const float*)d_in[24];
    const float* be4 = (const float*)d_in[25];
    const float* Wh1 = (const float*)d_in[26];
    const float* bh1 = (const float*)d_in[27];
    const float* Wh2 = (const float*)d_in[28];
    const float* bh2 = (const float*)d_in[29];
    float* out = (float*)d_out;

    // workspace layout
    char* p = (char*)d_ws;
    auto alloc = [&](size_t bytes) {
        void* r = (void*)p;
        p += (bytes + 255) & ~(size_t)255;
        return r;
    };
    float* bufA = (float*)alloc((size_t)N_NODES * 256 * 4);  // xW1, then xW_l (layers 2-4)
    float* bufB = (float*)alloc((size_t)N_NODES * 256 * 4);  // x1,  then h
    float* es1 = (float*)alloc((size_t)N_NODES * 4 * 4);
    float* ed1 = (float*)alloc((size_t)N_NODES * 4 * 4);
    float* esL = (float*)alloc((size_t)N_NODES * 4);
    float* edL = (float*)alloc((size_t)N_NODES * 4);
    int* offs = (int*)alloc((size_t)N_NODES * 4);
    int* csr = (int*)alloc((size_t)N_EDGES * 4);
    int* bounds = (int*)alloc((size_t)(N_GRAPHS + 1) * 4);
    float* hpool = (float*)alloc((size_t)N_GRAPHS * 64 * 4);
    char* z0 = p;  // everything below gets zeroed each call
    int* deg = (int*)alloc((size_t)N_NODES * 4);
    int* cur = (int*)alloc((size_t)N_NODES * 4);
    size_t zbytes = (size_t)(p - z0);
    hipMemsetAsync(z0, 0, zbytes, stream);

    const int edgeBlocks = (N_EDGES + 255) / 256;
    const int gemmBlocks = (N_NODES + 31) / 32;
    const int waveBlocks = (N_NODES * 64 + 255) / 256;

    // CSR build + graph bounds
    k_deg<<<edgeBlocks, 256, 0, stream>>>(ei, deg);
    k_scan<<<1, 1024, 0, stream>>>(deg, offs);
    k_fill<<<edgeBlocks, 256, 0, stream>>>(ei, offs, cur, csr);
    k_bounds<<<1, 128, 0, stream>>>(batch, bounds);

    // layer 1: GAT(128 -> 4x64, concat) + relu
    k_gemm<128, 256><<<gemmBlocks, 256, 0, stream>>>(x, W1, bufA, N_NODES);
    k_dots4<<<waveBlocks, 256, 0, stream>>>(bufA, a_src1, a_dst1, es1, ed1);
    k_gat1<<<waveBlocks, 256, 0, stream>>>(bufA, es1, ed1, offs, deg, csr, b1, bufB);

    // layer 2: GAT(256 -> 64) + BN + relu
    k_gemm<256, 64><<<gemmBlocks, 256, 0, stream>>>(bufB, W2, bufA, N_NODES);
    k_dots1<<<waveBlocks, 256, 0, stream>>>(bufA, a_src2, a_dst2, esL, edL);
    k_gatL<false><<<waveBlocks, 256, 0, stream>>>(bufA, esL, edL, offs, deg, csr, b2, g2, be2, bufB);

    // layer 3: residual GAT(64 -> 64) + BN + relu
    k_gemm<64, 64><<<gemmBlocks, 256, 0, stream>>>(bufB, W3, bufA, N_NODES);
    k_dots1<<<waveBlocks, 256, 0, stream>>>(bufA, a_src3, a_dst3, esL, edL);
    k_gatL<true><<<waveBlocks, 256, 0, stream>>>(bufA, esL, edL, offs, deg, csr, b3, g3, be3, bufB);

    // layer 4: residual GAT(64 -> 64) + BN + relu
    k_gemm<64, 64><<<gemmBlocks, 256, 0, stream>>>(bufB, W4, bufA, N_NODES);
    k_dots1<<<waveBlocks, 256, 0, stream>>>(bufA, a_src4, a_dst4, esL, edL);
    k_gatL<true><<<waveBlocks, 256, 0, stream>>>(bufA, esL, edL, offs, deg, csr, b4, g4, be4, bufB);

    // pool + head (batch sorted -> contiguous ranges, no atomics)
    k_pool2<<<N_GRAPHS, 256, 0, stream>>>(bufB, bounds, hpool);
    k_head<<<1, 256, 0, stream>>>(hpool, Wh1, bh1, Wh2, bh2, out);
}

// Round 3
// 896.617 us; speedup vs baseline: 1.4560x; 1.0592x over previous
//
#include <hip/hip_runtime.h>

#define N_NODES 50000
#define N_EDGES 800000
#define N_GRAPHS 64
#define F_IN 128
#define F_HID 64
#define N_HEADS 4
#define N_CLASSES 10
#define NEG_SLOPE 0.2f
// 1/sqrt(1 + 1e-5), BN eval-mode scale
#define BN_RSQ 0.9999950000374997f

__device__ __forceinline__ float lrelu(float v) { return v > 0.0f ? v : NEG_SLOPE * v; }

// bf16 <-> f32 (round-to-nearest-even; NaN not a concern for this workload)
__device__ __forceinline__ float b2f(unsigned short u) {
    return __uint_as_float(((unsigned int)u) << 16);
}
__device__ __forceinline__ unsigned short f2b(float f) {
    unsigned int u = __float_as_uint(f);
    return (unsigned short)((u + 0x7fffu + ((u >> 16) & 1u)) >> 16);
}

// ---------------- CSR build (per call; edge list is restored every call) ----------------
__global__ void k_deg(const int* __restrict__ ei, int* __restrict__ deg) {
    int e = blockIdx.x * blockDim.x + threadIdx.x;
    if (e < N_EDGES) atomicAdd(&deg[ei[N_EDGES + e]], 1);
}

__global__ void k_scan(const int* __restrict__ deg, int* __restrict__ offs) {
    __shared__ int sbuf[1024];
    const int t = threadIdx.x;
    const int CH = (N_NODES + 1023) / 1024;  // 49
    int base = t * CH;
    int s = 0;
    for (int i = 0; i < CH; ++i) { int idx = base + i; if (idx < N_NODES) s += deg[idx]; }
    sbuf[t] = s;
    __syncthreads();
    for (int off = 1; off < 1024; off <<= 1) {
        int v = (t >= off) ? sbuf[t - off] : 0;
        __syncthreads();
        sbuf[t] += v;
        __syncthreads();
    }
    int run = (t == 0) ? 0 : sbuf[t - 1];
    for (int i = 0; i < CH; ++i) {
        int idx = base + i;
        if (idx < N_NODES) { offs[idx] = run; run += deg[idx]; }
    }
}

__global__ void k_fill(const int* __restrict__ ei, const int* __restrict__ offs,
                       int* __restrict__ cur, int* __restrict__ csr_src) {
    int e = blockIdx.x * blockDim.x + threadIdx.x;
    if (e < N_EDGES) {
        int d = ei[N_EDGES + e];
        int pos = offs[d] + atomicAdd(&cur[d], 1);
        csr_src[pos] = ei[e];
    }
}

// graph boundaries: batch is sorted, so graph g owns nodes [bounds[g], bounds[g+1])
__global__ void k_bounds(const int* __restrict__ batch, int* __restrict__ bounds) {
    int g = threadIdx.x;
    if (g > N_GRAPHS) return;
    int lo = 0, hi = N_NODES;
    while (lo < hi) {
        int mid = (lo + hi) >> 1;
        if (batch[mid] < g) lo = mid + 1; else hi = mid;
    }
    bounds[g] = lo;
}

// ---------------- GEMM: out[N,J] = X[N,K] @ W[K,J], bf16 output ----------------
template <int K, int J>
__global__ __launch_bounds__(256) void k_gemm(const float* __restrict__ X,
                                              const float* __restrict__ W,
                                              unsigned short* __restrict__ out, int Nrows) {
    constexpr int TM = 32;
    constexpr int GROUPS = 256 / J;  // 1 (J=256) or 4 (J=64)
    constexpr int MPG = TM / GROUPS; // 32 or 8
    constexpr int LDK = K + 4;       // pad keeps float4 alignment, breaks bank stride
    __shared__ float xs[TM * LDK];
    const int tid = threadIdx.x;
    const int n0 = blockIdx.x * TM;
    for (int i = tid; i < TM * K; i += 256) {
        int r = i / K, c = i % K;
        int row = n0 + r;
        xs[r * LDK + c] = (row < Nrows) ? X[row * K + c] : 0.0f;
    }
    __syncthreads();
    const int col = tid % J;
    const int grp = tid / J;
    float acc[MPG];
#pragma unroll
    for (int m = 0; m < MPG; ++m) acc[m] = 0.0f;
    for (int k = 0; k < K; k += 4) {
        const float w0 = W[(k + 0) * J + col];
        const float w1 = W[(k + 1) * J + col];
        const float w2 = W[(k + 2) * J + col];
        const float w3 = W[(k + 3) * J + col];
#pragma unroll
        for (int m = 0; m < MPG; ++m) {
            const float4 x4 = *(const float4*)&xs[(grp * MPG + m) * LDK + k];
            acc[m] = fmaf(x4.x, w0, fmaf(x4.y, w1, fmaf(x4.z, w2, fmaf(x4.w, w3, acc[m]))));
        }
    }
#pragma unroll
    for (int m = 0; m < MPG; ++m) {
        int row = n0 + grp * MPG + m;
        if (row < Nrows) out[row * J + col] = f2b(acc[m]);
    }
}

// ---------------- attention score dots (bf16 xW, fp32 math) ----------------
__global__ void k_dots4(const unsigned short* __restrict__ xW, const float* __restrict__ asrc,
                        const float* __restrict__ adst, float* __restrict__ es,
                        float* __restrict__ ed) {
    int w = (blockIdx.x * blockDim.x + threadIdx.x) >> 6;
    int lane = threadIdx.x & 63;
    if (w >= N_NODES) return;
    const ushort4 xu = *(const ushort4*)&xW[w * 256 + lane * 4];
    const float4 as = *(const float4*)&asrc[lane * 4];
    const float4 ad = *(const float4*)&adst[lane * 4];
    const float x0 = b2f(xu.x), x1 = b2f(xu.y), x2 = b2f(xu.z), x3 = b2f(xu.w);
    float ss = x0 * as.x + x1 * as.y + x2 * as.z + x3 * as.w;
    float dd = x0 * ad.x + x1 * ad.y + x2 * ad.z + x3 * ad.w;
    for (int off = 1; off < 16; off <<= 1) {
        ss += __shfl_xor(ss, off);
        dd += __shfl_xor(dd, off);
    }
    if ((lane & 15) == 0) {
        es[w * 4 + (lane >> 4)] = ss;
        ed[w * 4 + (lane >> 4)] = dd;
    }
}

__global__ void k_dots1(const unsigned short* __restrict__ xW, const float* __restrict__ asrc,
                        const float* __restrict__ adst, float* __restrict__ es,
                        float* __restrict__ ed) {
    int w = (blockIdx.x * blockDim.x + threadIdx.x) >> 6;
    int lane = threadIdx.x & 63;
    if (w >= N_NODES) return;
    float xv = b2f(xW[w * 64 + lane]);
    float ss = xv * asrc[lane];
    float dd = xv * adst[lane];
    for (int off = 1; off < 64; off <<= 1) {
        ss += __shfl_xor(ss, off);
        dd += __shfl_xor(dd, off);
    }
    if (lane == 0) { es[w] = ss; ed[w] = dd; }
}

// ---------------- GAT layer 1: H=4, F=64, out 256, + bias + relu ----------------
__global__ __launch_bounds__(256) void k_gat1(
    const unsigned short* __restrict__ xW, const float* __restrict__ es, const float* __restrict__ ed,
    const int* __restrict__ offs, const int* __restrict__ deg, const int* __restrict__ csr,
    const float* __restrict__ bias, float* __restrict__ out) {
    const int n = (blockIdx.x * blockDim.x + threadIdx.x) >> 6;
    const int lane = threadIdx.x & 63;
    if (n >= N_NODES) return;
    const int off = offs[n];
    const int dg = deg[n];
    const float4 edv = *(const float4*)&ed[n * 4];
    const int head = lane >> 4;

    float m0 = -3.0e38f, m1 = -3.0e38f, m2 = -3.0e38f, m3 = -3.0e38f;
    for (int i = lane; i < dg; i += 64) {
        int s = csr[off + i];
        const float4 ev = *(const float4*)&es[s * 4];
        m0 = fmaxf(m0, lrelu(ev.x + edv.x));
        m1 = fmaxf(m1, lrelu(ev.y + edv.y));
        m2 = fmaxf(m2, lrelu(ev.z + edv.z));
        m3 = fmaxf(m3, lrelu(ev.w + edv.w));
    }
    for (int o = 1; o < 64; o <<= 1) {
        m0 = fmaxf(m0, __shfl_xor(m0, o));
        m1 = fmaxf(m1, __shfl_xor(m1, o));
        m2 = fmaxf(m2, __shfl_xor(m2, o));
        m3 = fmaxf(m3, __shfl_xor(m3, o));
    }

    float4 acc = make_float4(0.f, 0.f, 0.f, 0.f);
    float d0 = 0.f, d1 = 0.f, d2 = 0.f, d3 = 0.f;
    for (int base = 0; base < dg; base += 64) {
        int idx = base + lane;
        int s_l = 0;
        float p0 = 0.f, p1 = 0.f, p2 = 0.f, p3 = 0.f;
        if (idx < dg) {
            s_l = csr[off + idx];
            const float4 ev = *(const float4*)&es[s_l * 4];
            p0 = __expf(lrelu(ev.x + edv.x) - m0);
            p1 = __expf(lrelu(ev.y + edv.y) - m1);
            p2 = __expf(lrelu(ev.z + edv.z) - m2);
            p3 = __expf(lrelu(ev.w + edv.w) - m3);
        }
        d0 += p0; d1 += p1; d2 += p2; d3 += p3;
        const int cnt = min(64, dg - base);
        for (int j = 0; j < cnt; ++j) {
            const int sj = __shfl(s_l, j);
            const float q0 = __shfl(p0, j);
            const float q1 = __shfl(p1, j);
            const float q2 = __shfl(p2, j);
            const float q3 = __shfl(p3, j);
            const float psel = head == 0 ? q0 : head == 1 ? q1 : head == 2 ? q2 : q3;
            const ushort4 xu = *(const ushort4*)&xW[sj * 256 + lane * 4];
            acc.x = fmaf(psel, b2f(xu.x), acc.x);
            acc.y = fmaf(psel, b2f(xu.y), acc.y);
            acc.z = fmaf(psel, b2f(xu.z), acc.z);
            acc.w = fmaf(psel, b2f(xu.w), acc.w);
        }
    }
    for (int o = 1; o < 64; o <<= 1) {
        d0 += __shfl_xor(d0, o);
        d1 += __shfl_xor(d1, o);
        d2 += __shfl_xor(d2, o);
        d3 += __shfl_xor(d3, o);
    }
    const float dsel = head == 0 ? d0 : head == 1 ? d1 : head == 2 ? d2 : d3;
    const float inv = 1.0f / fmaxf(dsel, 1e-16f);
    const float4 bv = *(const float4*)&bias[lane * 4];
    float4 o4;
    o4.x = fmaxf(fmaf(acc.x, inv, bv.x), 0.f);
    o4.y = fmaxf(fmaf(acc.y, inv, bv.y), 0.f);
    o4.z = fmaxf(fmaf(acc.z, inv, bv.z), 0.f);
    o4.w = fmaxf(fmaf(acc.w, inv, bv.w), 0.f);
    *(float4*)&out[n * 256 + lane * 4] = o4;
}

// ---------------- GAT layers 2-4: H=1, F=64, + bias + BN + relu (+ residual) ----------------
template <bool RES>
__global__ __launch_bounds__(256) void k_gatL(
    const unsigned short* __restrict__ xW, const float* __restrict__ es, const float* __restrict__ ed,
    const int* __restrict__ offs, const int* __restrict__ deg, const int* __restrict__ csr,
    const float* __restrict__ bias, const float* __restrict__ gam, const float* __restrict__ bet,
    float* __restrict__ h) {
    const int n = (blockIdx.x * blockDim.x + threadIdx.x) >> 6;
    const int lane = threadIdx.x & 63;
    if (n >= N_NODES) return;
    const int off = offs[n];
    const int dg = deg[n];
    const float edn = ed[n];

    float m = -3.0e38f;
    for (int i = lane; i < dg; i += 64) {
        int s = csr[off + i];
        m = fmaxf(m, lrelu(es[s] + edn));
    }
    for (int o = 1; o < 64; o <<= 1) m = fmaxf(m, __shfl_xor(m, o));

    float acc = 0.f, dsum = 0.f;
    for (int base = 0; base < dg; base += 64) {
        int idx = base + lane;
        int s_l = 0;
        float p_l = 0.f;
        if (idx < dg) {
            s_l = csr[off + idx];
            p_l = __expf(lrelu(es[s_l] + edn) - m);
        }
        dsum += p_l;
        const int cnt = min(64, dg - base);
        for (int j = 0; j < cnt; ++j) {
            const int sj = __shfl(s_l, j);
            const float pj = __shfl(p_l, j);
            acc = fmaf(pj, b2f(xW[sj * 64 + lane]), acc);
        }
    }
    for (int o = 1; o < 64; o <<= 1) dsum += __shfl_xor(dsum, o);

    const float y = acc / fmaxf(dsum, 1e-16f) + bias[lane];
    const float z = fmaxf(fmaf(gam[lane] * y, BN_RSQ, bet[lane]), 0.f);
    h[n * 64 + lane] = RES ? h[n * 64 + lane] + z : z;
}

// ---------------- mean pool: one block per graph, contiguous node range, no atomics ----------------
__global__ __launch_bounds__(256) void k_pool2(const float* __restrict__ h,
                                               const int* __restrict__ bounds,
                                               float* __restrict__ hp) {
    __shared__ float part[4][64];
    const int g = blockIdx.x;
    const int lane = threadIdx.x & 63;
    const int wid = threadIdx.x >> 6;
    const int s = bounds[g], e = bounds[g + 1];
    float acc = 0.f;
    for (int n = s + wid; n < e; n += 4) acc += h[n * 64 + lane];
    part[wid][lane] = acc;
    __syncthreads();
    if (wid == 0) {
        float v = part[0][lane] + part[1][lane] + part[2][lane] + part[3][lane];
        hp[g * 64 + lane] = v / fmaxf((float)(e - s), 1.0f);
    }
}

// ---------------- MLP head, single block (hp already mean-pooled) ----------------
__global__ __launch_bounds__(256) void k_head(const float* __restrict__ hpg,
                                              const float* __restrict__ Wh1,
                                              const float* __restrict__ bh1,
                                              const float* __restrict__ Wh2,
                                              const float* __restrict__ bh2,
                                              float* __restrict__ out) {
    __shared__ float hp[64 * 64];
    __shared__ float t1[64 * 128];
    const int tid = threadIdx.x;
    for (int i = tid; i < 64 * 64; i += 256) hp[i] = hpg[i];
    __syncthreads();
    for (int i = tid; i < 64 * 128; i += 256) {
        int g = i >> 7, j = i & 127;
        float s = bh1[j];
        for (int k = 0; k < 64; ++k) s = fmaf(hp[g * 64 + k], Wh1[k * 128 + j], s);
        t1[i] = fmaxf(s, 0.f);
    }
    __syncthreads();
    for (int i = tid; i < 640; i += 256) {
        int g = i / 10, j = i - g * 10;
        float s = bh2[j];
        for (int k = 0; k < 128; ++k) s = fmaf(t1[g * 128 + k], Wh2[k * 10 + j], s);
        out[i] = s;
    }
}

extern "C" void kernel_launch(void* const* d_in, const int* in_sizes, int n_in,
                              void* d_out, int out_size, void* d_ws, size_t ws_size,
                              hipStream_t stream) {
    const float* x = (const float*)d_in[1];
    const int* ei = (const int*)d_in[2];
    const int* batch = (const int*)d_in[3];
    const float* W1 = (const float*)d_in[4];
    const float* a_src1 = (const float*)d_in[5];
    const float* a_dst1 = (const float*)d_in[6];
    const float* b1 = (const float*)d_in[7];
    const float* W2 = (const float*)d_in[8];
    const float* a_src2 = (const float*)d_in[9];
    const float* a_dst2 = (const float*)d_in[10];
    const float* b2 = (const float*)d_in[11];
    const float* g2 = (const float*)d_in[12];
    const float* be2 = (const float*)d_in[13];
    const float* W3 = (const float*)d_in[14];
    const float* a_src3 = (const float*)d_in[15];
    const float* a_dst3 = (const float*)d_in[16];
    const float* b3 = (const float*)d_in[17];
    const float* g3 = (const float*)d_in[18];
    const float* be3 = (const float*)d_in[19];
    const float* W4 = (const float*)d_in[20];
    const float* a_src4 = (const float*)d_in[21];
    const float* a_dst4 = (const float*)d_in[22];
    const float* b4 = (const float*)d_in[23];
    const float* g4 = (const float*)d_in[24];
    const float* be4 = (const float*)d_in[25];
    const float* Wh1 = (const float*)d_in[26];
    const float* bh1 = (const float*)d_in[27];
    const float* Wh2 = (const float*)d_in[28];
    const float* bh2 = (const float*)d_in[29];
    float* out = (float*)d_out;

    // workspace layout
    char* p = (char*)d_ws;
    auto alloc = [&](size_t bytes) {
        void* r = (void*)p;
        p += (bytes + 255) & ~(size_t)255;
        return r;
    };
    unsigned short* bufA = (unsigned short*)alloc((size_t)N_NODES * 256 * 2);  // xW (bf16), per layer
    float* bufB = (float*)alloc((size_t)N_NODES * 256 * 4);  // x1, then h (fp32, streamed)
    float* es1 = (float*)alloc((size_t)N_NODES * 4 * 4);
    float* ed1 = (float*)alloc((size_t)N_NODES * 4 * 4);
    float* esL = (float*)alloc((size_t)N_NODES * 4);
    float* edL = (float*)alloc((size_t)N_NODES * 4);
    int* offs = (int*)alloc((size_t)N_NODES * 4);
    int* csr = (int*)alloc((size_t)N_EDGES * 4);
    int* bounds = (int*)alloc((size_t)(N_GRAPHS + 1) * 4);
    float* hpool = (float*)alloc((size_t)N_GRAPHS * 64 * 4);
    char* z0 = p;  // everything below gets zeroed each call
    int* deg = (int*)alloc((size_t)N_NODES * 4);
    int* cur = (int*)alloc((size_t)N_NODES * 4);
    size_t zbytes = (size_t)(p - z0);
    hipMemsetAsync(z0, 0, zbytes, stream);

    const int edgeBlocks = (N_EDGES + 255) / 256;
    const int gemmBlocks = (N_NODES + 31) / 32;
    const int waveBlocks = (N_NODES * 64 + 255) / 256;

    // CSR build + graph bounds
    k_deg<<<edgeBlocks, 256, 0, stream>>>(ei, deg);
    k_scan<<<1, 1024, 0, stream>>>(deg, offs);
    k_fill<<<edgeBlocks, 256, 0, stream>>>(ei, offs, cur, csr);
    k_bounds<<<1, 128, 0, stream>>>(batch, bounds);

    // layer 1: GAT(128 -> 4x64, concat) + relu
    k_gemm<128, 256><<<gemmBlocks, 256, 0, stream>>>(x, W1, bufA, N_NODES);
    k_dots4<<<waveBlocks, 256, 0, stream>>>(bufA, a_src1, a_dst1, es1, ed1);
    k_gat1<<<waveBlocks, 256, 0, stream>>>(bufA, es1, ed1, offs, deg, csr, b1, bufB);

    // layer 2: GAT(256 -> 64) + BN + relu
    k_gemm<256, 64><<<gemmBlocks, 256, 0, stream>>>(bufB, W2, bufA, N_NODES);
    k_dots1<<<waveBlocks, 256, 0, stream>>>(bufA, a_src2, a_dst2, esL, edL);
    k_gatL<false><<<waveBlocks, 256, 0, stream>>>(bufA, esL, edL, offs, deg, csr, b2, g2, be2, bufB);

    // layer 3: residual GAT(64 -> 64) + BN + relu
    k_gemm<64, 64><<<gemmBlocks, 256, 0, stream>>>(bufB, W3, bufA, N_NODES);
    k_dots1<<<waveBlocks, 256, 0, stream>>>(bufA, a_src3, a_dst3, esL, edL);
    k_gatL<true><<<waveBlocks, 256, 0, stream>>>(bufA, esL, edL, offs, deg, csr, b3, g3, be3, bufB);

    // layer 4: residual GAT(64 -> 64) + BN + relu
    k_gemm<64, 64><<<gemmBlocks, 256, 0, stream>>>(bufB, W4, bufA, N_NODES);
    k_dots1<<<waveBlocks, 256, 0, stream>>>(bufA, a_src4, a_dst4, esL, edL);
    k_gatL<true><<<waveBlocks, 256, 0, stream>>>(bufA, esL, edL, offs, deg, csr, b4, g4, be4, bufB);

    // pool + head (batch sorted -> contiguous ranges, no atomics)
    k_pool2<<<N_GRAPHS, 256, 0, stream>>>(bufB, bounds, hpool);
    k_head<<<1, 256, 0, stream>>>(hpool, Wh1, bh1, Wh2, bh2, out);
}

// Round 4
// 676.534 us; speedup vs baseline: 1.9296x; 1.3253x over previous
//
#include <hip/hip_runtime.h>

#define N_NODES 50000
#define N_EDGES 800000
#define N_GRAPHS 64
#define F_IN 128
#define F_HID 64
#define N_HEADS 4
#define N_CLASSES 10
#define NEG_SLOPE 0.2f
// 1/sqrt(1 + 1e-5), BN eval-mode scale
#define BN_RSQ 0.9999950000374997f

typedef __bf16 bf16x8 __attribute__((ext_vector_type(8)));
typedef float floatx4 __attribute__((ext_vector_type(4)));

__device__ __forceinline__ float lrelu(float v) { return v > 0.0f ? v : NEG_SLOPE * v; }

// bf16 <-> f32 (round-to-nearest-even)
__device__ __forceinline__ float b2f(unsigned short u) {
    return __uint_as_float(((unsigned int)u) << 16);
}
__device__ __forceinline__ unsigned short f2b(float f) {
    unsigned int u = __float_as_uint(f);
    return (unsigned short)((u + 0x7fffu + ((u >> 16) & 1u)) >> 16);
}

// ---------------- CSR build (per call; edge list is restored every call) ----------------
__global__ void k_deg(const int* __restrict__ ei, int* __restrict__ deg) {
    int e = blockIdx.x * blockDim.x + threadIdx.x;
    if (e < N_EDGES) atomicAdd(&deg[ei[N_EDGES + e]], 1);
}

// offsets via wave shuffle-scan + one atomic per wave. Node order of segments is
// arbitrary (run-to-run nondeterministic) but CSR only needs disjoint ranges.
__global__ void k_offs(const int* __restrict__ deg, int* __restrict__ offs,
                       int* __restrict__ total) {
    int i = blockIdx.x * blockDim.x + threadIdx.x;
    int lane = threadIdx.x & 63;
    int v = (i < N_NODES) ? deg[i] : 0;
    int incl = v;
    for (int o = 1; o < 64; o <<= 1) {
        int t = __shfl_up(incl, o);
        if (lane >= o) incl += t;
    }
    int wtot = __shfl(incl, 63);
    int base = 0;
    if (lane == 0) base = atomicAdd(total, wtot);
    base = __shfl(base, 0);
    if (i < N_NODES) offs[i] = base + incl - v;
}

__global__ void k_fill(const int* __restrict__ ei, const int* __restrict__ offs,
                       int* __restrict__ cur, int* __restrict__ csr_src) {
    int e = blockIdx.x * blockDim.x + threadIdx.x;
    if (e < N_EDGES) {
        int d = ei[N_EDGES + e];
        int pos = offs[d] + atomicAdd(&cur[d], 1);
        csr_src[pos] = ei[e];
    }
}

// graph boundaries: batch is sorted, so graph g owns nodes [bounds[g], bounds[g+1])
__global__ void k_bounds(const int* __restrict__ batch, int* __restrict__ bounds) {
    int g = threadIdx.x;
    if (g > N_GRAPHS) return;
    int lo = 0, hi = N_NODES;
    while (lo < hi) {
        int mid = (lo + hi) >> 1;
        if (batch[mid] < g) lo = mid + 1; else hi = mid;
    }
    bounds[g] = lo;
}

// ---------------- weight prep: Wt[n*K+k] = bf16(W[k*N+n]) ----------------
__global__ void k_prepw(const float* __restrict__ W, unsigned short* __restrict__ Wt,
                        int K, int N) {
    int i = blockIdx.x * blockDim.x + threadIdx.x;
    if (i < K * N) {
        int k = i / N, n = i % N;
        Wt[n * K + k] = f2b(W[i]);
    }
}

// ---------------- MFMA GEMM: out_bf16[rows,N] = A[rows,K] @ Wt^T ----------------
// Block: 64 rows staged to LDS; 4 waves, wave w owns rows w*16..w*16+15, loops N/16 col tiles.
// Fragment layouts (m89/m91-verified): A[m=lane&15][k=quad*8+j]; B[k=quad*8+j][n=lane&15]
// (Wt stored [N][K] so B-frag is one contiguous 16B load); C/D row=quad*4+reg, col=lane&15.
template <int K, int N, bool AF32>
__global__ __launch_bounds__(256) void k_mgemm(const void* __restrict__ Ap,
                                               const unsigned short* __restrict__ Bt,
                                               unsigned short* __restrict__ out,
                                               int rows) {
    constexpr int LDP = K + 8;  // bf16 elems; rows stay 16B-aligned, conflicts <=2-way (free)
    __shared__ unsigned short As[64 * LDP];
    const int tid = threadIdx.x;
    const int r0 = blockIdx.x * 64;
    if (AF32) {
        const float* A = (const float*)Ap;
        for (int i = tid; i < 16 * K; i += 256) {  // 64*K/4 float4 ops
            int r = i / (K / 4), c4 = i % (K / 4);
            int row = r0 + r;
            float4 v = (row < rows) ? *(const float4*)&A[(size_t)row * K + c4 * 4]
                                    : make_float4(0.f, 0.f, 0.f, 0.f);
            ushort4 u;
            u.x = f2b(v.x); u.y = f2b(v.y); u.z = f2b(v.z); u.w = f2b(v.w);
            *(ushort4*)&As[r * LDP + c4 * 4] = u;
        }
    } else {
        const unsigned short* A = (const unsigned short*)Ap;
        for (int i = tid; i < 8 * K; i += 256) {  // 64*K/8 16B ops
            int r = i / (K / 8), c8 = i % (K / 8);
            int row = r0 + r;
            uint4 v;
            if (row < rows) v = *(const uint4*)&A[(size_t)row * K + c8 * 8];
            else { v.x = v.y = v.z = v.w = 0; }
            *(uint4*)&As[r * LDP + c8 * 8] = v;
        }
    }
    __syncthreads();
    const int w = tid >> 6, lane = tid & 63;
    const int quad = lane >> 4, l16 = lane & 15;
    bf16x8 afrag[K / 32];
#pragma unroll
    for (int kk = 0; kk < K / 32; ++kk)
        afrag[kk] = *(const bf16x8*)&As[(w * 16 + l16) * LDP + kk * 32 + quad * 8];
#pragma unroll 1
    for (int ct = 0; ct < N / 16; ++ct) {
        floatx4 acc = {0.f, 0.f, 0.f, 0.f};
#pragma unroll
        for (int kk = 0; kk < K / 32; ++kk) {
            const bf16x8 bfrag =
                *(const bf16x8*)&Bt[(size_t)(ct * 16 + l16) * K + kk * 32 + quad * 8];
            acc = __builtin_amdgcn_mfma_f32_16x16x32_bf16(afrag[kk], bfrag, acc, 0, 0, 0);
        }
        const int gr0 = r0 + w * 16 + quad * 4;
        const int gc = ct * 16 + l16;
#pragma unroll
        for (int rg = 0; rg < 4; ++rg) {
            int gr = gr0 + rg;
            if (gr < rows) out[(size_t)gr * N + gc] = f2b(acc[rg]);
        }
    }
}

// ---------------- attention score dots (bf16 xW, fp32 math) ----------------
__global__ void k_dots4(const unsigned short* __restrict__ xW, const float* __restrict__ asrc,
                        const float* __restrict__ adst, float* __restrict__ es,
                        float* __restrict__ ed) {
    int w = (blockIdx.x * blockDim.x + threadIdx.x) >> 6;
    int lane = threadIdx.x & 63;
    if (w >= N_NODES) return;
    const ushort4 xu = *(const ushort4*)&xW[w * 256 + lane * 4];
    const float4 as = *(const float4*)&asrc[lane * 4];
    const float4 ad = *(const float4*)&adst[lane * 4];
    const float x0 = b2f(xu.x), x1 = b2f(xu.y), x2 = b2f(xu.z), x3 = b2f(xu.w);
    float ss = x0 * as.x + x1 * as.y + x2 * as.z + x3 * as.w;
    float dd = x0 * ad.x + x1 * ad.y + x2 * ad.z + x3 * ad.w;
    for (int off = 1; off < 16; off <<= 1) {
        ss += __shfl_xor(ss, off);
        dd += __shfl_xor(dd, off);
    }
    if ((lane & 15) == 0) {
        es[w * 4 + (lane >> 4)] = ss;
        ed[w * 4 + (lane >> 4)] = dd;
    }
}

__global__ void k_dots1(const unsigned short* __restrict__ xW, const float* __restrict__ asrc,
                        const float* __restrict__ adst, float* __restrict__ es,
                        float* __restrict__ ed) {
    int w = (blockIdx.x * blockDim.x + threadIdx.x) >> 6;
    int lane = threadIdx.x & 63;
    if (w >= N_NODES) return;
    float xv = b2f(xW[w * 64 + lane]);
    float ss = xv * asrc[lane];
    float dd = xv * adst[lane];
    for (int off = 1; off < 64; off <<= 1) {
        ss += __shfl_xor(ss, off);
        dd += __shfl_xor(dd, off);
    }
    if (lane == 0) { es[w] = ss; ed[w] = dd; }
}

// ---------------- GAT layer 1: H=4, F=64, out 256 (bf16), + bias + relu ----------------
__global__ __launch_bounds__(256) void k_gat1(
    const unsigned short* __restrict__ xW, const float* __restrict__ es, const float* __restrict__ ed,
    const int* __restrict__ offs, const int* __restrict__ deg, const int* __restrict__ csr,
    const float* __restrict__ bias, unsigned short* __restrict__ out) {
    const int n = (blockIdx.x * blockDim.x + threadIdx.x) >> 6;
    const int lane = threadIdx.x & 63;
    if (n >= N_NODES) return;
    const int off = offs[n];
    const int dg = deg[n];
    const float4 edv = *(const float4*)&ed[n * 4];
    const int head = lane >> 4;

    float m0 = -3.0e38f, m1 = -3.0e38f, m2 = -3.0e38f, m3 = -3.0e38f;
    for (int i = lane; i < dg; i += 64) {
        int s = csr[off + i];
        const float4 ev = *(const float4*)&es[s * 4];
        m0 = fmaxf(m0, lrelu(ev.x + edv.x));
        m1 = fmaxf(m1, lrelu(ev.y + edv.y));
        m2 = fmaxf(m2, lrelu(ev.z + edv.z));
        m3 = fmaxf(m3, lrelu(ev.w + edv.w));
    }
    for (int o = 1; o < 64; o <<= 1) {
        m0 = fmaxf(m0, __shfl_xor(m0, o));
        m1 = fmaxf(m1, __shfl_xor(m1, o));
        m2 = fmaxf(m2, __shfl_xor(m2, o));
        m3 = fmaxf(m3, __shfl_xor(m3, o));
    }

    float4 acc = make_float4(0.f, 0.f, 0.f, 0.f);
    float d0 = 0.f, d1 = 0.f, d2 = 0.f, d3 = 0.f;
    for (int base = 0; base < dg; base += 64) {
        int idx = base + lane;
        int s_l = 0;
        float p0 = 0.f, p1 = 0.f, p2 = 0.f, p3 = 0.f;
        if (idx < dg) {
            s_l = csr[off + idx];
            const float4 ev = *(const float4*)&es[s_l * 4];
            p0 = __expf(lrelu(ev.x + edv.x) - m0);
            p1 = __expf(lrelu(ev.y + edv.y) - m1);
            p2 = __expf(lrelu(ev.z + edv.z) - m2);
            p3 = __expf(lrelu(ev.w + edv.w) - m3);
        }
        d0 += p0; d1 += p1; d2 += p2; d3 += p3;
        const int cnt = min(64, dg - base);
        for (int j = 0; j < cnt; ++j) {
            const int sj = __shfl(s_l, j);
            const float q0 = __shfl(p0, j);
            const float q1 = __shfl(p1, j);
            const float q2 = __shfl(p2, j);
            const float q3 = __shfl(p3, j);
            const float psel = head == 0 ? q0 : head == 1 ? q1 : head == 2 ? q2 : q3;
            const ushort4 xu = *(const ushort4*)&xW[sj * 256 + lane * 4];
            acc.x = fmaf(psel, b2f(xu.x), acc.x);
            acc.y = fmaf(psel, b2f(xu.y), acc.y);
            acc.z = fmaf(psel, b2f(xu.z), acc.z);
            acc.w = fmaf(psel, b2f(xu.w), acc.w);
        }
    }
    for (int o = 1; o < 64; o <<= 1) {
        d0 += __shfl_xor(d0, o);
        d1 += __shfl_xor(d1, o);
        d2 += __shfl_xor(d2, o);
        d3 += __shfl_xor(d3, o);
    }
    const float dsel = head == 0 ? d0 : head == 1 ? d1 : head == 2 ? d2 : d3;
    const float inv = 1.0f / fmaxf(dsel, 1e-16f);
    const float4 bv = *(const float4*)&bias[lane * 4];
    ushort4 o4;
    o4.x = f2b(fmaxf(fmaf(acc.x, inv, bv.x), 0.f));
    o4.y = f2b(fmaxf(fmaf(acc.y, inv, bv.y), 0.f));
    o4.z = f2b(fmaxf(fmaf(acc.z, inv, bv.z), 0.f));
    o4.w = f2b(fmaxf(fmaf(acc.w, inv, bv.w), 0.f));
    *(ushort4*)&out[n * 256 + lane * 4] = o4;
}

// ---------------- GAT layers 2-4: H=1, F=64, + bias + BN + relu (+ residual) ----------------
// writes h (fp32, for residual/pool) and hb (bf16, GEMM input for next layer)
template <bool RES>
__global__ __launch_bounds__(256) void k_gatL(
    const unsigned short* __restrict__ xW, const float* __restrict__ es, const float* __restrict__ ed,
    const int* __restrict__ offs, const int* __restrict__ deg, const int* __restrict__ csr,
    const float* __restrict__ bias, const float* __restrict__ gam, const float* __restrict__ bet,
    float* __restrict__ h, unsigned short* __restrict__ hb) {
    const int n = (blockIdx.x * blockDim.x + threadIdx.x) >> 6;
    const int lane = threadIdx.x & 63;
    if (n >= N_NODES) return;
    const int off = offs[n];
    const int dg = deg[n];
    const float edn = ed[n];

    float m = -3.0e38f;
    for (int i = lane; i < dg; i += 64) {
        int s = csr[off + i];
        m = fmaxf(m, lrelu(es[s] + edn));
    }
    for (int o = 1; o < 64; o <<= 1) m = fmaxf(m, __shfl_xor(m, o));

    float acc = 0.f, dsum = 0.f;
    for (int base = 0; base < dg; base += 64) {
        int idx = base + lane;
        int s_l = 0;
        float p_l = 0.f;
        if (idx < dg) {
            s_l = csr[off + idx];
            p_l = __expf(lrelu(es[s_l] + edn) - m);
        }
        dsum += p_l;
        const int cnt = min(64, dg - base);
        for (int j = 0; j < cnt; ++j) {
            const int sj = __shfl(s_l, j);
            const float pj = __shfl(p_l, j);
            acc = fmaf(pj, b2f(xW[sj * 64 + lane]), acc);
        }
    }
    for (int o = 1; o < 64; o <<= 1) dsum += __shfl_xor(dsum, o);

    const float y = acc / fmaxf(dsum, 1e-16f) + bias[lane];
    const float z = fmaxf(fmaf(gam[lane] * y, BN_RSQ, bet[lane]), 0.f);
    const float hn = RES ? h[n * 64 + lane] + z : z;
    h[n * 64 + lane] = hn;
    hb[n * 64 + lane] = f2b(hn);
}

// ---------------- mean pool: one block per graph, contiguous node range, no atomics ----------------
__global__ __launch_bounds__(256) void k_pool2(const float* __restrict__ h,
                                               const int* __restrict__ bounds,
                                               float* __restrict__ hp) {
    __shared__ float part[4][64];
    const int g = blockIdx.x;
    const int lane = threadIdx.x & 63;
    const int wid = threadIdx.x >> 6;
    const int s = bounds[g], e = bounds[g + 1];
    float acc = 0.f;
    for (int n = s + wid; n < e; n += 4) acc += h[n * 64 + lane];
    part[wid][lane] = acc;
    __syncthreads();
    if (wid == 0) {
        float v = part[0][lane] + part[1][lane] + part[2][lane] + part[3][lane];
        hp[g * 64 + lane] = v / fmaxf((float)(e - s), 1.0f);
    }
}

// ---------------- MLP head, single block (hp already mean-pooled) ----------------
__global__ __launch_bounds__(256) void k_head(const float* __restrict__ hpg,
                                              const float* __restrict__ Wh1,
                                              const float* __restrict__ bh1,
                                              const float* __restrict__ Wh2,
                                              const float* __restrict__ bh2,
                                              float* __restrict__ out) {
    __shared__ float hp[64 * 64];
    __shared__ float t1[64 * 128];
    const int tid = threadIdx.x;
    for (int i = tid; i < 64 * 64; i += 256) hp[i] = hpg[i];
    __syncthreads();
    for (int i = tid; i < 64 * 128; i += 256) {
        int g = i >> 7, j = i & 127;
        float s = bh1[j];
        for (int k = 0; k < 64; ++k) s = fmaf(hp[g * 64 + k], Wh1[k * 128 + j], s);
        t1[i] = fmaxf(s, 0.f);
    }
    __syncthreads();
    for (int i = tid; i < 640; i += 256) {
        int g = i / 10, j = i - g * 10;
        float s = bh2[j];
        for (int k = 0; k < 128; ++k) s = fmaf(t1[g * 128 + k], Wh2[k * 10 + j], s);
        out[i] = s;
    }
}

extern "C" void kernel_launch(void* const* d_in, const int* in_sizes, int n_in,
                              void* d_out, int out_size, void* d_ws, size_t ws_size,
                              hipStream_t stream) {
    const float* x = (const float*)d_in[1];
    const int* ei = (const int*)d_in[2];
    const int* batch = (const int*)d_in[3];
    const float* W1 = (const float*)d_in[4];
    const float* a_src1 = (const float*)d_in[5];
    const float* a_dst1 = (const float*)d_in[6];
    const float* b1 = (const float*)d_in[7];
    const float* W2 = (const float*)d_in[8];
    const float* a_src2 = (const float*)d_in[9];
    const float* a_dst2 = (const float*)d_in[10];
    const float* b2 = (const float*)d_in[11];
    const float* g2 = (const float*)d_in[12];
    const float* be2 = (const float*)d_in[13];
    const float* W3 = (const float*)d_in[14];
    const float* a_src3 = (const float*)d_in[15];
    const float* a_dst3 = (const float*)d_in[16];
    const float* b3 = (const float*)d_in[17];
    const float* g3 = (const float*)d_in[18];
    const float* be3 = (const float*)d_in[19];
    const float* W4 = (const float*)d_in[20];
    const float* a_src4 = (const float*)d_in[21];
    const float* a_dst4 = (const float*)d_in[22];
    const float* b4 = (const float*)d_in[23];
    const float* g4 = (const float*)d_in[24];
    const float* be4 = (const float*)d_in[25];
    const float* Wh1 = (const float*)d_in[26];
    const float* bh1 = (const float*)d_in[27];
    const float* Wh2 = (const float*)d_in[28];
    const float* bh2 = (const float*)d_in[29];
    float* out = (float*)d_out;

    // workspace layout
    char* p = (char*)d_ws;
    auto alloc = [&](size_t bytes) {
        void* r = (void*)p;
        p += (bytes + 255) & ~(size_t)255;
        return r;
    };
    unsigned short* bufA = (unsigned short*)alloc((size_t)N_NODES * 256 * 2);  // xW bf16 per layer
    unsigned short* x1b = (unsigned short*)alloc((size_t)N_NODES * 256 * 2);   // x1 bf16
    float* h = (float*)alloc((size_t)N_NODES * 64 * 4);                        // h fp32
    unsigned short* hb = (unsigned short*)alloc((size_t)N_NODES * 64 * 2);     // h bf16
    float* es1 = (float*)alloc((size_t)N_NODES * 4 * 4);
    float* ed1 = (float*)alloc((size_t)N_NODES * 4 * 4);
    float* esL = (float*)alloc((size_t)N_NODES * 4);
    float* edL = (float*)alloc((size_t)N_NODES * 4);
    int* offs = (int*)alloc((size_t)N_NODES * 4);
    int* csr = (int*)alloc((size_t)N_EDGES * 4);
    int* bounds = (int*)alloc((size_t)(N_GRAPHS + 1) * 4);
    float* hpool = (float*)alloc((size_t)N_GRAPHS * 64 * 4);
    unsigned short* Wt1 = (unsigned short*)alloc((size_t)128 * 256 * 2);
    unsigned short* Wt2 = (unsigned short*)alloc((size_t)256 * 64 * 2);
    unsigned short* Wt3 = (unsigned short*)alloc((size_t)64 * 64 * 2);
    unsigned short* Wt4 = (unsigned short*)alloc((size_t)64 * 64 * 2);
    char* z0 = p;  // everything below gets zeroed each call
    int* deg = (int*)alloc((size_t)N_NODES * 4);
    int* cur = (int*)alloc((size_t)N_NODES * 4);
    int* total = (int*)alloc(256);
    size_t zbytes = (size_t)(p - z0);
    hipMemsetAsync(z0, 0, zbytes, stream);

    const int edgeBlocks = (N_EDGES + 255) / 256;
    const int nodeBlocks = (N_NODES + 255) / 256;
    const int mgemmBlocks = (N_NODES + 63) / 64;
    const int waveBlocks = (N_NODES * 64 + 255) / 256;

    // weight prep (bf16 transpose)
    k_prepw<<<(128 * 256 + 255) / 256, 256, 0, stream>>>(W1, Wt1, 128, 256);
    k_prepw<<<(256 * 64 + 255) / 256, 256, 0, stream>>>(W2, Wt2, 256, 64);
    k_prepw<<<(64 * 64 + 255) / 256, 256, 0, stream>>>(W3, Wt3, 64, 64);
    k_prepw<<<(64 * 64 + 255) / 256, 256, 0, stream>>>(W4, Wt4, 64, 64);

    // CSR build + graph bounds
    k_deg<<<edgeBlocks, 256, 0, stream>>>(ei, deg);
    k_offs<<<nodeBlocks, 256, 0, stream>>>(deg, offs, total);
    k_fill<<<edgeBlocks, 256, 0, stream>>>(ei, offs, cur, csr);
    k_bounds<<<1, 128, 0, stream>>>(batch, bounds);

    // layer 1: GAT(128 -> 4x64, concat) + relu
    k_mgemm<128, 256, true><<<mgemmBlocks, 256, 0, stream>>>(x, Wt1, bufA, N_NODES);
    k_dots4<<<waveBlocks, 256, 0, stream>>>(bufA, a_src1, a_dst1, es1, ed1);
    k_gat1<<<waveBlocks, 256, 0, stream>>>(bufA, es1, ed1, offs, deg, csr, b1, x1b);

    // layer 2: GAT(256 -> 64) + BN + relu
    k_mgemm<256, 64, false><<<mgemmBlocks, 256, 0, stream>>>(x1b, Wt2, bufA, N_NODES);
    k_dots1<<<waveBlocks, 256, 0, stream>>>(bufA, a_src2, a_dst2, esL, edL);
    k_gatL<false><<<waveBlocks, 256, 0, stream>>>(bufA, esL, edL, offs, deg, csr, b2, g2, be2, h, hb);

    // layer 3: residual GAT(64 -> 64) + BN + relu
    k_mgemm<64, 64, false><<<mgemmBlocks, 256, 0, stream>>>(hb, Wt3, bufA, N_NODES);
    k_dots1<<<waveBlocks, 256, 0, stream>>>(bufA, a_src3, a_dst3, esL, edL);
    k_gatL<true><<<waveBlocks, 256, 0, stream>>>(bufA, esL, edL, offs, deg, csr, b3, g3, be3, h, hb);

    // layer 4: residual GAT(64 -> 64) + BN + relu
    k_mgemm<64, 64, false><<<mgemmBlocks, 256, 0, stream>>>(hb, Wt4, bufA, N_NODES);
    k_dots1<<<waveBlocks, 256, 0, stream>>>(bufA, a_src4, a_dst4, esL, edL);
    k_gatL<true><<<waveBlocks, 256, 0, stream>>>(bufA, esL, edL, offs, deg, csr, b4, g4, be4, h, hb);

    // pool + head (batch sorted -> contiguous ranges, no atomics)
    k_pool2<<<N_GRAPHS, 256, 0, stream>>>(h, bounds, hpool);
    k_head<<<1, 256, 0, stream>>>(hpool, Wh1, bh1, Wh2, bh2, out);
}

// Round 5
// 590.176 us; speedup vs baseline: 2.2120x; 1.1463x over previous
//
#include <hip/hip_runtime.h>

#define N_NODES 50000
#define N_EDGES 800000
#define N_GRAPHS 64
#define F_IN 128
#define F_HID 64
#define N_HEADS 4
#define N_CLASSES 10
#define NEG_SLOPE 0.2f
// 1/sqrt(1 + 1e-5), BN eval-mode scale
#define BN_RSQ 0.9999950000374997f

typedef __bf16 bf16x8 __attribute__((ext_vector_type(8)));
typedef float floatx4 __attribute__((ext_vector_type(4)));

__device__ __forceinline__ float lrelu(float v) { return v > 0.0f ? v : NEG_SLOPE * v; }

// bf16 <-> f32 (round-to-nearest-even)
__device__ __forceinline__ float b2f(unsigned short u) {
    return __uint_as_float(((unsigned int)u) << 16);
}
__device__ __forceinline__ unsigned short f2b(float f) {
    unsigned int u = __float_as_uint(f);
    return (unsigned short)((u + 0x7fffu + ((u >> 16) & 1u)) >> 16);
}
// unpack 2 bf16 from one dword (2 instrs: shl / and)
__device__ __forceinline__ float blo(unsigned int d) { return __uint_as_float(d << 16); }
__device__ __forceinline__ float bhi(unsigned int d) { return __uint_as_float(d & 0xffff0000u); }

// ---------------- CSR build (per call; edge list is restored every call) ----------------
__global__ void k_deg(const int* __restrict__ ei, int* __restrict__ deg) {
    int e = blockIdx.x * blockDim.x + threadIdx.x;
    if (e < N_EDGES) atomicAdd(&deg[ei[N_EDGES + e]], 1);
}

// offsets via wave shuffle-scan + one atomic per wave (segment order arbitrary; CSR only
// needs disjoint ranges).
__global__ void k_offs(const int* __restrict__ deg, int* __restrict__ offs,
                       int* __restrict__ total) {
    int i = blockIdx.x * blockDim.x + threadIdx.x;
    int lane = threadIdx.x & 63;
    int v = (i < N_NODES) ? deg[i] : 0;
    int incl = v;
    for (int o = 1; o < 64; o <<= 1) {
        int t = __shfl_up(incl, o);
        if (lane >= o) incl += t;
    }
    int wtot = __shfl(incl, 63);
    int base = 0;
    if (lane == 0) base = atomicAdd(total, wtot);
    base = __shfl(base, 0);
    if (i < N_NODES) offs[i] = base + incl - v;
}

__global__ void k_fill(const int* __restrict__ ei, const int* __restrict__ offs,
                       int* __restrict__ cur, int* __restrict__ csr_src) {
    int e = blockIdx.x * blockDim.x + threadIdx.x;
    if (e < N_EDGES) {
        int d = ei[N_EDGES + e];
        int pos = offs[d] + atomicAdd(&cur[d], 1);
        csr_src[pos] = ei[e];
    }
}

// graph boundaries: batch is sorted, so graph g owns nodes [bounds[g], bounds[g+1])
__global__ void k_bounds(const int* __restrict__ batch, int* __restrict__ bounds) {
    int g = threadIdx.x;
    if (g > N_GRAPHS) return;
    int lo = 0, hi = N_NODES;
    while (lo < hi) {
        int mid = (lo + hi) >> 1;
        if (batch[mid] < g) lo = mid + 1; else hi = mid;
    }
    bounds[g] = lo;
}

// ---------------- weight prep: Wt[n*K+k] = bf16(W[k*N+n]) ----------------
__global__ void k_prepw(const float* __restrict__ W, unsigned short* __restrict__ Wt,
                        int K, int N) {
    int i = blockIdx.x * blockDim.x + threadIdx.x;
    if (i < K * N) {
        int k = i / N, n = i % N;
        Wt[n * K + k] = f2b(W[i]);
    }
}

// ---------------- MFMA GEMM: out_bf16[rows,N] = A[rows,K] @ Wt^T ----------------
template <int K, int N, bool AF32>
__global__ __launch_bounds__(256) void k_mgemm(const void* __restrict__ Ap,
                                               const unsigned short* __restrict__ Bt,
                                               unsigned short* __restrict__ out,
                                               int rows) {
    constexpr int LDP = K + 8;  // bf16 elems; rows stay 16B-aligned, conflicts <=2-way (free)
    __shared__ unsigned short As[64 * LDP];
    const int tid = threadIdx.x;
    const int r0 = blockIdx.x * 64;
    if (AF32) {
        const float* A = (const float*)Ap;
        for (int i = tid; i < 16 * K; i += 256) {
            int r = i / (K / 4), c4 = i % (K / 4);
            int row = r0 + r;
            float4 v = (row < rows) ? *(const float4*)&A[(size_t)row * K + c4 * 4]
                                    : make_float4(0.f, 0.f, 0.f, 0.f);
            ushort4 u;
            u.x = f2b(v.x); u.y = f2b(v.y); u.z = f2b(v.z); u.w = f2b(v.w);
            *(ushort4*)&As[r * LDP + c4 * 4] = u;
        }
    } else {
        const unsigned short* A = (const unsigned short*)Ap;
        for (int i = tid; i < 8 * K; i += 256) {
            int r = i / (K / 8), c8 = i % (K / 8);
            int row = r0 + r;
            uint4 v;
            if (row < rows) v = *(const uint4*)&A[(size_t)row * K + c8 * 8];
            else { v.x = v.y = v.z = v.w = 0; }
            *(uint4*)&As[r * LDP + c8 * 8] = v;
        }
    }
    __syncthreads();
    const int w = tid >> 6, lane = tid & 63;
    const int quad = lane >> 4, l16 = lane & 15;
    bf16x8 afrag[K / 32];
#pragma unroll
    for (int kk = 0; kk < K / 32; ++kk)
        afrag[kk] = *(const bf16x8*)&As[(w * 16 + l16) * LDP + kk * 32 + quad * 8];
#pragma unroll 1
    for (int ct = 0; ct < N / 16; ++ct) {
        floatx4 acc = {0.f, 0.f, 0.f, 0.f};
#pragma unroll
        for (int kk = 0; kk < K / 32; ++kk) {
            const bf16x8 bfrag =
                *(const bf16x8*)&Bt[(size_t)(ct * 16 + l16) * K + kk * 32 + quad * 8];
            acc = __builtin_amdgcn_mfma_f32_16x16x32_bf16(afrag[kk], bfrag, acc, 0, 0, 0);
        }
        const int gr0 = r0 + w * 16 + quad * 4;
        const int gc = ct * 16 + l16;
#pragma unroll
        for (int rg = 0; rg < 4; ++rg) {
            int gr = gr0 + rg;
            if (gr < rows) out[(size_t)gr * N + gc] = f2b(acc[rg]);
        }
    }
}

// ---------------- attention score dots (bf16 xW, fp32 math) ----------------
__global__ void k_dots4(const unsigned short* __restrict__ xW, const float* __restrict__ asrc,
                        const float* __restrict__ adst, float* __restrict__ es,
                        float* __restrict__ ed) {
    int w = (blockIdx.x * blockDim.x + threadIdx.x) >> 6;
    int lane = threadIdx.x & 63;
    if (w >= N_NODES) return;
    const ushort4 xu = *(const ushort4*)&xW[w * 256 + lane * 4];
    const float4 as = *(const float4*)&asrc[lane * 4];
    const float4 ad = *(const float4*)&adst[lane * 4];
    const float x0 = b2f(xu.x), x1 = b2f(xu.y), x2 = b2f(xu.z), x3 = b2f(xu.w);
    float ss = x0 * as.x + x1 * as.y + x2 * as.z + x3 * as.w;
    float dd = x0 * ad.x + x1 * ad.y + x2 * ad.z + x3 * ad.w;
    for (int off = 1; off < 16; off <<= 1) {
        ss += __shfl_xor(ss, off);
        dd += __shfl_xor(dd, off);
    }
    if ((lane & 15) == 0) {
        es[w * 4 + (lane >> 4)] = ss;
        ed[w * 4 + (lane >> 4)] = dd;
    }
}

__global__ void k_dots1(const unsigned short* __restrict__ xW, const float* __restrict__ asrc,
                        const float* __restrict__ adst, float* __restrict__ es,
                        float* __restrict__ ed) {
    int w = (blockIdx.x * blockDim.x + threadIdx.x) >> 6;
    int lane = threadIdx.x & 63;
    if (w >= N_NODES) return;
    float xv = b2f(xW[w * 64 + lane]);
    float ss = xv * asrc[lane];
    float dd = xv * adst[lane];
    for (int off = 1; off < 64; off <<= 1) {
        ss += __shfl_xor(ss, off);
        dd += __shfl_xor(dd, off);
    }
    if (lane == 0) { es[w] = ss; ed[w] = dd; }
}

// ---------------- GAT layer 1: H=4, F=64, out 256 (bf16), + bias + relu ----------------
// One wave per dst node. Edge chunks of 64 staged (src, p[4]) to LDS; inner loop runs
// 4 edges in parallel via 16-lane groups (lane = grp*16 + t; lane covers cols t*16..+15,
// head hq = t>>2). Tail edges read p=0 from LDS -> no predication needed.
__global__ __launch_bounds__(256) void k_gat1(
    const unsigned short* __restrict__ xW, const float* __restrict__ es, const float* __restrict__ ed,
    const int* __restrict__ offs, const int* __restrict__ deg, const int* __restrict__ csr,
    const float* __restrict__ bias, unsigned short* __restrict__ out) {
    __shared__ float ps[4][256];
    __shared__ int sbuf[4][64];
    const int wv = threadIdx.x >> 6;
    const int lane = threadIdx.x & 63;
    const int n = blockIdx.x * 4 + wv;
    if (n >= N_NODES) return;
    const int off = offs[n];
    const int dg = deg[n];
    const float4 edv = *(const float4*)&ed[n * 4];
    const int t = lane & 15, grp = lane >> 4, hq = t >> 2;

    // pass 1: per-head max (lane-parallel over edges)
    float m0 = -3.0e38f, m1 = -3.0e38f, m2 = -3.0e38f, m3 = -3.0e38f;
    for (int i = lane; i < dg; i += 64) {
        int s = csr[off + i];
        const float4 ev = *(const float4*)&es[s * 4];
        m0 = fmaxf(m0, lrelu(ev.x + edv.x));
        m1 = fmaxf(m1, lrelu(ev.y + edv.y));
        m2 = fmaxf(m2, lrelu(ev.z + edv.z));
        m3 = fmaxf(m3, lrelu(ev.w + edv.w));
    }
    for (int o = 1; o < 64; o <<= 1) {
        m0 = fmaxf(m0, __shfl_xor(m0, o));
        m1 = fmaxf(m1, __shfl_xor(m1, o));
        m2 = fmaxf(m2, __shfl_xor(m2, o));
        m3 = fmaxf(m3, __shfl_xor(m3, o));
    }

    float acc[16];
#pragma unroll
    for (int k = 0; k < 16; ++k) acc[k] = 0.f;
    float d0 = 0.f, d1 = 0.f, d2 = 0.f, d3 = 0.f;

    for (int base = 0; base < dg; base += 64) {
        const int idx = base + lane;
        int s_l = 0;
        float p0 = 0.f, p1 = 0.f, p2 = 0.f, p3 = 0.f;
        if (idx < dg) {
            s_l = csr[off + idx];
            const float4 ev = *(const float4*)&es[s_l * 4];
            p0 = __expf(lrelu(ev.x + edv.x) - m0);
            p1 = __expf(lrelu(ev.y + edv.y) - m1);
            p2 = __expf(lrelu(ev.z + edv.z) - m2);
            p3 = __expf(lrelu(ev.w + edv.w) - m3);
        }
        d0 += p0; d1 += p1; d2 += p2; d3 += p3;
        *(float4*)&ps[wv][lane * 4] = make_float4(p0, p1, p2, p3);
        sbuf[wv][lane] = s_l;
        const int cnt = min(64, dg - base);
        for (int j4 = 0; j4 < cnt; j4 += 4) {
            const int j = j4 + grp;
            const float pj = ps[wv][j * 4 + hq];
            const int sj = sbuf[wv][j];
            const uint4 a = *(const uint4*)&xW[(size_t)sj * 256 + t * 16];
            const uint4 b = *(const uint4*)&xW[(size_t)sj * 256 + t * 16 + 8];
            acc[0]  = fmaf(pj, blo(a.x), acc[0]);
            acc[1]  = fmaf(pj, bhi(a.x), acc[1]);
            acc[2]  = fmaf(pj, blo(a.y), acc[2]);
            acc[3]  = fmaf(pj, bhi(a.y), acc[3]);
            acc[4]  = fmaf(pj, blo(a.z), acc[4]);
            acc[5]  = fmaf(pj, bhi(a.z), acc[5]);
            acc[6]  = fmaf(pj, blo(a.w), acc[6]);
            acc[7]  = fmaf(pj, bhi(a.w), acc[7]);
            acc[8]  = fmaf(pj, blo(b.x), acc[8]);
            acc[9]  = fmaf(pj, bhi(b.x), acc[9]);
            acc[10] = fmaf(pj, blo(b.y), acc[10]);
            acc[11] = fmaf(pj, bhi(b.y), acc[11]);
            acc[12] = fmaf(pj, blo(b.z), acc[12]);
            acc[13] = fmaf(pj, bhi(b.z), acc[13]);
            acc[14] = fmaf(pj, blo(b.w), acc[14]);
            acc[15] = fmaf(pj, bhi(b.w), acc[15]);
        }
    }
    // combine the 4 groups' partial sums (lanes g*16+t share the same cols)
#pragma unroll
    for (int k = 0; k < 16; ++k) {
        acc[k] += __shfl_xor(acc[k], 16);
        acc[k] += __shfl_xor(acc[k], 32);
    }
    for (int o = 1; o < 64; o <<= 1) {
        d0 += __shfl_xor(d0, o);
        d1 += __shfl_xor(d1, o);
        d2 += __shfl_xor(d2, o);
        d3 += __shfl_xor(d3, o);
    }
    if (grp == 0) {
        const float dsel = hq == 0 ? d0 : hq == 1 ? d1 : hq == 2 ? d2 : d3;
        const float inv = 1.0f / fmaxf(dsel, 1e-16f);
#pragma unroll
        for (int k4 = 0; k4 < 16; k4 += 4) {
            const int c = t * 16 + k4;
            const float4 bv = *(const float4*)&bias[c];
            ushort4 o4;
            o4.x = f2b(fmaxf(fmaf(acc[k4 + 0], inv, bv.x), 0.f));
            o4.y = f2b(fmaxf(fmaf(acc[k4 + 1], inv, bv.y), 0.f));
            o4.z = f2b(fmaxf(fmaf(acc[k4 + 2], inv, bv.z), 0.f));
            o4.w = f2b(fmaxf(fmaf(acc[k4 + 3], inv, bv.w), 0.f));
            *(ushort4*)&out[(size_t)n * 256 + c] = o4;
        }
    }
}

// ---------------- GAT layers 2-4: H=1, F=64, + bias + BN + relu (+ residual) ----------------
// Same structure: 8-lane groups, 8 edges in parallel; lane covers cols t*8..t*8+7.
template <bool RES>
__global__ __launch_bounds__(256) void k_gatL(
    const unsigned short* __restrict__ xW, const float* __restrict__ es, const float* __restrict__ ed,
    const int* __restrict__ offs, const int* __restrict__ deg, const int* __restrict__ csr,
    const float* __restrict__ bias, const float* __restrict__ gam, const float* __restrict__ bet,
    float* __restrict__ h, unsigned short* __restrict__ hb) {
    __shared__ float ps[4][64];
    __shared__ int sbuf[4][64];
    const int wv = threadIdx.x >> 6;
    const int lane = threadIdx.x & 63;
    const int n = blockIdx.x * 4 + wv;
    if (n >= N_NODES) return;
    const int off = offs[n];
    const int dg = deg[n];
    const float edn = ed[n];
    const int t = lane & 7, grp = lane >> 3;

    float m = -3.0e38f;
    for (int i = lane; i < dg; i += 64) {
        int s = csr[off + i];
        m = fmaxf(m, lrelu(es[s] + edn));
    }
    for (int o = 1; o < 64; o <<= 1) m = fmaxf(m, __shfl_xor(m, o));

    float acc[8];
#pragma unroll
    for (int k = 0; k < 8; ++k) acc[k] = 0.f;
    float dsum = 0.f;

    for (int base = 0; base < dg; base += 64) {
        const int idx = base + lane;
        int s_l = 0;
        float p_l = 0.f;
        if (idx < dg) {
            s_l = csr[off + idx];
            p_l = __expf(lrelu(es[s_l] + edn) - m);
        }
        dsum += p_l;
        ps[wv][lane] = p_l;
        sbuf[wv][lane] = s_l;
        const int cnt = min(64, dg - base);
        for (int j8 = 0; j8 < cnt; j8 += 8) {
            const int j = j8 + grp;
            const float pj = ps[wv][j];
            const int sj = sbuf[wv][j];
            const uint4 a = *(const uint4*)&xW[(size_t)sj * 64 + t * 8];
            acc[0] = fmaf(pj, blo(a.x), acc[0]);
            acc[1] = fmaf(pj, bhi(a.x), acc[1]);
            acc[2] = fmaf(pj, blo(a.y), acc[2]);
            acc[3] = fmaf(pj, bhi(a.y), acc[3]);
            acc[4] = fmaf(pj, blo(a.z), acc[4]);
            acc[5] = fmaf(pj, bhi(a.z), acc[5]);
            acc[6] = fmaf(pj, blo(a.w), acc[6]);
            acc[7] = fmaf(pj, bhi(a.w), acc[7]);
        }
    }
#pragma unroll
    for (int k = 0; k < 8; ++k) {
        acc[k] += __shfl_xor(acc[k], 8);
        acc[k] += __shfl_xor(acc[k], 16);
        acc[k] += __shfl_xor(acc[k], 32);
    }
    for (int o = 1; o < 64; o <<= 1) dsum += __shfl_xor(dsum, o);

    if (grp == 0) {
        const float inv = 1.0f / fmaxf(dsum, 1e-16f);
        const int c0 = t * 8;
        float hn[8];
#pragma unroll
        for (int k = 0; k < 8; ++k) {
            const int c = c0 + k;
            const float y = fmaf(acc[k], inv, bias[c]);
            const float z = fmaxf(fmaf(gam[c] * y, BN_RSQ, bet[c]), 0.f);
            hn[k] = RES ? h[(size_t)n * 64 + c] + z : z;
        }
        *(float4*)&h[(size_t)n * 64 + c0] = make_float4(hn[0], hn[1], hn[2], hn[3]);
        *(float4*)&h[(size_t)n * 64 + c0 + 4] = make_float4(hn[4], hn[5], hn[6], hn[7]);
        ushort4 u0, u1;
        u0.x = f2b(hn[0]); u0.y = f2b(hn[1]); u0.z = f2b(hn[2]); u0.w = f2b(hn[3]);
        u1.x = f2b(hn[4]); u1.y = f2b(hn[5]); u1.z = f2b(hn[6]); u1.w = f2b(hn[7]);
        *(ushort4*)&hb[(size_t)n * 64 + c0] = u0;
        *(ushort4*)&hb[(size_t)n * 64 + c0 + 4] = u1;
    }
}

// ---------------- mean pool: one block per graph, contiguous node range, no atomics ----------------
__global__ __launch_bounds__(256) void k_pool2(const float* __restrict__ h,
                                               const int* __restrict__ bounds,
                                               float* __restrict__ hp) {
    __shared__ float part[4][64];
    const int g = blockIdx.x;
    const int lane = threadIdx.x & 63;
    const int wid = threadIdx.x >> 6;
    const int s = bounds[g], e = bounds[g + 1];
    float acc = 0.f;
    for (int n = s + wid; n < e; n += 4) acc += h[n * 64 + lane];
    part[wid][lane] = acc;
    __syncthreads();
    if (wid == 0) {
        float v = part[0][lane] + part[1][lane] + part[2][lane] + part[3][lane];
        hp[g * 64 + lane] = v / fmaxf((float)(e - s), 1.0f);
    }
}

// ---------------- MLP head, single block (hp already mean-pooled) ----------------
__global__ __launch_bounds__(256) void k_head(const float* __restrict__ hpg,
                                              const float* __restrict__ Wh1,
                                              const float* __restrict__ bh1,
                                              const float* __restrict__ Wh2,
                                              const float* __restrict__ bh2,
                                              float* __restrict__ out) {
    __shared__ float hp[64 * 64];
    __shared__ float t1[64 * 128];
    const int tid = threadIdx.x;
    for (int i = tid; i < 64 * 64; i += 256) hp[i] = hpg[i];
    __syncthreads();
    for (int i = tid; i < 64 * 128; i += 256) {
        int g = i >> 7, j = i & 127;
        float s = bh1[j];
        for (int k = 0; k < 64; ++k) s = fmaf(hp[g * 64 + k], Wh1[k * 128 + j], s);
        t1[i] = fmaxf(s, 0.f);
    }
    __syncthreads();
    for (int i = tid; i < 640; i += 256) {
        int g = i / 10, j = i - g * 10;
        float s = bh2[j];
        for (int k = 0; k < 128; ++k) s = fmaf(t1[g * 128 + k], Wh2[k * 10 + j], s);
        out[i] = s;
    }
}

extern "C" void kernel_launch(void* const* d_in, const int* in_sizes, int n_in,
                              void* d_out, int out_size, void* d_ws, size_t ws_size,
                              hipStream_t stream) {
    const float* x = (const float*)d_in[1];
    const int* ei = (const int*)d_in[2];
    const int* batch = (const int*)d_in[3];
    const float* W1 = (const float*)d_in[4];
    const float* a_src1 = (const float*)d_in[5];
    const float* a_dst1 = (const float*)d_in[6];
    const float* b1 = (const float*)d_in[7];
    const float* W2 = (const float*)d_in[8];
    const float* a_src2 = (const float*)d_in[9];
    const float* a_dst2 = (const float*)d_in[10];
    const float* b2 = (const float*)d_in[11];
    const float* g2 = (const float*)d_in[12];
    const float* be2 = (const float*)d_in[13];
    const float* W3 = (const float*)d_in[14];
    const float* a_src3 = (const float*)d_in[15];
    const float* a_dst3 = (const float*)d_in[16];
    const float* b3 = (const float*)d_in[17];
    const float* g3 = (const float*)d_in[18];
    const float* be3 = (const float*)d_in[19];
    const float* W4 = (const float*)d_in[20];
    const float* a_src4 = (const float*)d_in[21];
    const float* a_dst4 = (const float*)d_in[22];
    const float* b4 = (const float*)d_in[23];
    const float* g4 = (const float*)d_in[24];
    const float* be4 = (const float*)d_in[25];
    const float* Wh1 = (const float*)d_in[26];
    const float* bh1 = (const float*)d_in[27];
    const float* Wh2 = (const float*)d_in[28];
    const float* bh2 = (const float*)d_in[29];
    float* out = (float*)d_out;

    // workspace layout
    char* p = (char*)d_ws;
    auto alloc = [&](size_t bytes) {
        void* r = (void*)p;
        p += (bytes + 255) & ~(size_t)255;
        return r;
    };
    unsigned short* bufA = (unsigned short*)alloc((size_t)N_NODES * 256 * 2);  // xW bf16 per layer
    unsigned short* x1b = (unsigned short*)alloc((size_t)N_NODES * 256 * 2);   // x1 bf16
    float* h = (float*)alloc((size_t)N_NODES * 64 * 4);                        // h fp32
    unsigned short* hb = (unsigned short*)alloc((size_t)N_NODES * 64 * 2);     // h bf16
    float* es1 = (float*)alloc((size_t)N_NODES * 4 * 4);
    float* ed1 = (float*)alloc((size_t)N_NODES * 4 * 4);
    float* esL = (float*)alloc((size_t)N_NODES * 4);
    float* edL = (float*)alloc((size_t)N_NODES * 4);
    int* offs = (int*)alloc((size_t)N_NODES * 4);
    int* csr = (int*)alloc((size_t)N_EDGES * 4);
    int* bounds = (int*)alloc((size_t)(N_GRAPHS + 1) * 4);
    float* hpool = (float*)alloc((size_t)N_GRAPHS * 64 * 4);
    unsigned short* Wt1 = (unsigned short*)alloc((size_t)128 * 256 * 2);
    unsigned short* Wt2 = (unsigned short*)alloc((size_t)256 * 64 * 2);
    unsigned short* Wt3 = (unsigned short*)alloc((size_t)64 * 64 * 2);
    unsigned short* Wt4 = (unsigned short*)alloc((size_t)64 * 64 * 2);
    char* z0 = p;  // everything below gets zeroed each call
    int* deg = (int*)alloc((size_t)N_NODES * 4);
    int* cur = (int*)alloc((size_t)N_NODES * 4);
    int* total = (int*)alloc(256);
    size_t zbytes = (size_t)(p - z0);
    hipMemsetAsync(z0, 0, zbytes, stream);

    const int edgeBlocks = (N_EDGES + 255) / 256;
    const int nodeBlocks = (N_NODES + 255) / 256;
    const int mgemmBlocks = (N_NODES + 63) / 64;
    const int waveBlocks = (N_NODES * 64 + 255) / 256;   // one wave per node (dots)
    const int gatBlocks = (N_NODES + 3) / 4;             // 4 node-waves per block (gat)

    // weight prep (bf16 transpose)
    k_prepw<<<(128 * 256 + 255) / 256, 256, 0, stream>>>(W1, Wt1, 128, 256);
    k_prepw<<<(256 * 64 + 255) / 256, 256, 0, stream>>>(W2, Wt2, 256, 64);
    k_prepw<<<(64 * 64 + 255) / 256, 256, 0, stream>>>(W3, Wt3, 64, 64);
    k_prepw<<<(64 * 64 + 255) / 256, 256, 0, stream>>>(W4, Wt4, 64, 64);

    // CSR build + graph bounds
    k_deg<<<edgeBlocks, 256, 0, stream>>>(ei, deg);
    k_offs<<<nodeBlocks, 256, 0, stream>>>(deg, offs, total);
    k_fill<<<edgeBlocks, 256, 0, stream>>>(ei, offs, cur, csr);
    k_bounds<<<1, 128, 0, stream>>>(batch, bounds);

    // layer 1: GAT(128 -> 4x64, concat) + relu
    k_mgemm<128, 256, true><<<mgemmBlocks, 256, 0, stream>>>(x, Wt1, bufA, N_NODES);
    k_dots4<<<waveBlocks, 256, 0, stream>>>(bufA, a_src1, a_dst1, es1, ed1);
    k_gat1<<<gatBlocks, 256, 0, stream>>>(bufA, es1, ed1, offs, deg, csr, b1, x1b);

    // layer 2: GAT(256 -> 64) + BN + relu
    k_mgemm<256, 64, false><<<mgemmBlocks, 256, 0, stream>>>(x1b, Wt2, bufA, N_NODES);
    k_dots1<<<waveBlocks, 256, 0, stream>>>(bufA, a_src2, a_dst2, esL, edL);
    k_gatL<false><<<gatBlocks, 256, 0, stream>>>(bufA, esL, edL, offs, deg, csr, b2, g2, be2, h, hb);

    // layer 3: residual GAT(64 -> 64) + BN + relu
    k_mgemm<64, 64, false><<<mgemmBlocks, 256, 0, stream>>>(hb, Wt3, bufA, N_NODES);
    k_dots1<<<waveBlocks, 256, 0, stream>>>(bufA, a_src3, a_dst3, esL, edL);
    k_gatL<true><<<gatBlocks, 256, 0, stream>>>(bufA, esL, edL, offs, deg, csr, b3, g3, be3, h, hb);

    // layer 4: residual GAT(64 -> 64) + BN + relu
    k_mgemm<64, 64, false><<<mgemmBlocks, 256, 0, stream>>>(hb, Wt4, bufA, N_NODES);
    k_dots1<<<waveBlocks, 256, 0, stream>>>(bufA, a_src4, a_dst4, esL, edL);
    k_gatL<true><<<gatBlocks, 256, 0, stream>>>(bufA, esL, edL, offs, deg, csr, b4, g4, be4, h, hb);

    // pool + head (batch sorted -> contiguous ranges, no atomics)
    k_pool2<<<N_GRAPHS, 256, 0, stream>>>(h, bounds, hpool);
    k_head<<<1, 256, 0, stream>>>(hpool, Wh1, bh1, Wh2, bh2, out);
}

// Round 6
// 543.484 us; speedup vs baseline: 2.4020x; 1.0859x over previous
//
#include <hip/hip_runtime.h>

#define N_NODES 50000
#define N_EDGES 800000
#define N_GRAPHS 64
#define F_IN 128
#define F_HID 64
#define N_HEADS 4
#define N_CLASSES 10
#define NEG_SLOPE 0.2f
// 1/sqrt(1 + 1e-5), BN eval-mode scale
#define BN_RSQ 0.9999950000374997f

typedef __bf16 bf16x8 __attribute__((ext_vector_type(8)));
typedef float floatx4 __attribute__((ext_vector_type(4)));

__device__ __forceinline__ float lrelu(float v) { return v > 0.0f ? v : NEG_SLOPE * v; }

// bf16 <-> f32 (round-to-nearest-even)
__device__ __forceinline__ float b2f(unsigned short u) {
    return __uint_as_float(((unsigned int)u) << 16);
}
__device__ __forceinline__ unsigned short f2b(float f) {
    unsigned int u = __float_as_uint(f);
    return (unsigned short)((u + 0x7fffu + ((u >> 16) & 1u)) >> 16);
}
// unpack 2 bf16 from one dword (1 instr each: shl / and)
__device__ __forceinline__ float blo(unsigned int d) { return __uint_as_float(d << 16); }
__device__ __forceinline__ float bhi(unsigned int d) { return __uint_as_float(d & 0xffff0000u); }

// ---------------- CSR build (per call; edge list is restored every call) ----------------
__global__ void k_deg(const int* __restrict__ ei, int* __restrict__ deg) {
    int e = blockIdx.x * blockDim.x + threadIdx.x;
    if (e < N_EDGES) atomicAdd(&deg[ei[N_EDGES + e]], 1);
}

// offsets via wave shuffle-scan + one atomic per wave (segment order arbitrary; CSR only
// needs disjoint ranges).
__global__ void k_offs(const int* __restrict__ deg, int* __restrict__ offs,
                       int* __restrict__ total) {
    int i = blockIdx.x * blockDim.x + threadIdx.x;
    int lane = threadIdx.x & 63;
    int v = (i < N_NODES) ? deg[i] : 0;
    int incl = v;
    for (int o = 1; o < 64; o <<= 1) {
        int t = __shfl_up(incl, o);
        if (lane >= o) incl += t;
    }
    int wtot = __shfl(incl, 63);
    int base = 0;
    if (lane == 0) base = atomicAdd(total, wtot);
    base = __shfl(base, 0);
    if (i < N_NODES) offs[i] = base + incl - v;
}

__global__ void k_fill(const int* __restrict__ ei, const int* __restrict__ offs,
                       int* __restrict__ cur, int* __restrict__ csr_src) {
    int e = blockIdx.x * blockDim.x + threadIdx.x;
    if (e < N_EDGES) {
        int d = ei[N_EDGES + e];
        int pos = offs[d] + atomicAdd(&cur[d], 1);
        csr_src[pos] = ei[e];
    }
}

// graph boundaries: batch is sorted, so graph g owns nodes [bounds[g], bounds[g+1])
__global__ void k_bounds(const int* __restrict__ batch, int* __restrict__ bounds) {
    int g = threadIdx.x;
    if (g > N_GRAPHS) return;
    int lo = 0, hi = N_NODES;
    while (lo < hi) {
        int mid = (lo + hi) >> 1;
        if (batch[mid] < g) lo = mid + 1; else hi = mid;
    }
    bounds[g] = lo;
}

// ---------------- weight prep: Wt[n*K+k] = bf16(W[k*N+n]) ----------------
__global__ void k_prepw(const float* __restrict__ W, unsigned short* __restrict__ Wt,
                        int K, int N) {
    int i = blockIdx.x * blockDim.x + threadIdx.x;
    if (i < K * N) {
        int k = i / N, n = i % N;
        Wt[n * K + k] = f2b(W[i]);
    }
}

// ---------------- MFMA GEMM + fused attention dots ----------------
// out_bf16[rows,N] = A[rows,K] @ Wt^T; es/ed[row][h] = dot(xW_row_head, a_src/a_dst[h])
// computed from the fp32 accumulators (more accurate than re-reading bf16).
// C/D layout (m89-verified): row=quad*4+rg, col=ct*16+l16.
template <int K, int N, int HEADS, bool AF32>
__global__ __launch_bounds__(256) void k_mgemm(const void* __restrict__ Ap,
                                               const unsigned short* __restrict__ Bt,
                                               const float* __restrict__ asrc,
                                               const float* __restrict__ adst,
                                               unsigned short* __restrict__ out,
                                               float* __restrict__ es,
                                               float* __restrict__ ed, int rows) {
    constexpr int LDP = K + 8;  // bf16 elems; rows stay 16B-aligned, conflicts <=2-way (free)
    __shared__ unsigned short As[64 * LDP];
    const int tid = threadIdx.x;
    const int r0 = blockIdx.x * 64;
    if (AF32) {
        const float* A = (const float*)Ap;
        for (int i = tid; i < 16 * K; i += 256) {
            int r = i / (K / 4), c4 = i % (K / 4);
            int row = r0 + r;
            float4 v = (row < rows) ? *(const float4*)&A[(size_t)row * K + c4 * 4]
                                    : make_float4(0.f, 0.f, 0.f, 0.f);
            ushort4 u;
            u.x = f2b(v.x); u.y = f2b(v.y); u.z = f2b(v.z); u.w = f2b(v.w);
            *(ushort4*)&As[r * LDP + c4 * 4] = u;
        }
    } else {
        const unsigned short* A = (const unsigned short*)Ap;
        for (int i = tid; i < 8 * K; i += 256) {
            int r = i / (K / 8), c8 = i % (K / 8);
            int row = r0 + r;
            uint4 v;
            if (row < rows) v = *(const uint4*)&A[(size_t)row * K + c8 * 8];
            else { v.x = v.y = v.z = v.w = 0; }
            *(uint4*)&As[r * LDP + c8 * 8] = v;
        }
    }
    __syncthreads();
    const int w = tid >> 6, lane = tid & 63;
    const int quad = lane >> 4, l16 = lane & 15;
    const int gr0 = r0 + w * 16 + quad * 4;
    bf16x8 afrag[K / 32];
#pragma unroll
    for (int kk = 0; kk < K / 32; ++kk)
        afrag[kk] = *(const bf16x8*)&As[(w * 16 + l16) * LDP + kk * 32 + quad * 8];
    float sacc[4] = {0.f, 0.f, 0.f, 0.f};
    float dacc[4] = {0.f, 0.f, 0.f, 0.f};
#pragma unroll 1
    for (int ct = 0; ct < N / 16; ++ct) {
        floatx4 acc = {0.f, 0.f, 0.f, 0.f};
#pragma unroll
        for (int kk = 0; kk < K / 32; ++kk) {
            const bf16x8 bfrag =
                *(const bf16x8*)&Bt[(size_t)(ct * 16 + l16) * K + kk * 32 + quad * 8];
            acc = __builtin_amdgcn_mfma_f32_16x16x32_bf16(afrag[kk], bfrag, acc, 0, 0, 0);
        }
        const int gc = ct * 16 + l16;
        // fused attention dots: head = gc / 64, feat = gc % 64
        const int hh = gc >> 6;
        const float av = asrc[gc & (64 * HEADS > N ? N - 1 : 63) + (hh << 6) - (hh << 6)
                              ];  // placeholder avoided below
        (void)av;
        {
            const int f = gc & 63;
            const float as = asrc[hh * 64 + f];
            const float ad = adst[hh * 64 + f];
#pragma unroll
            for (int rg = 0; rg < 4; ++rg) {
                sacc[rg] = fmaf(acc[rg], as, sacc[rg]);
                dacc[rg] = fmaf(acc[rg], ad, dacc[rg]);
            }
        }
#pragma unroll
        for (int rg = 0; rg < 4; ++rg) {
            int gr = gr0 + rg;
            if (gr < rows) out[(size_t)gr * N + gc] = f2b(acc[rg]);
        }
        // head boundary every 64 cols (4 ct tiles): reduce over the 16 l16 lanes and store
        if ((ct & 3) == 3) {
#pragma unroll
            for (int rg = 0; rg < 4; ++rg) {
                float s = sacc[rg], d = dacc[rg];
                for (int o = 1; o < 16; o <<= 1) {
                    s += __shfl_xor(s, o);
                    d += __shfl_xor(d, o);
                }
                if (l16 == 0) {
                    int gr = gr0 + rg;
                    if (gr < rows) {
                        es[(size_t)gr * HEADS + hh] = s;
                        ed[(size_t)gr * HEADS + hh] = d;
                    }
                }
                sacc[rg] = 0.f;
                dacc[rg] = 0.f;
            }
        }
    }
}

// ---------------- GAT layer 1: H=4, F=64, out 256 (bf16), + bias + relu ----------------
// Single pass (no segment-max: scores are O(1), exp cannot overflow; alpha is
// shift-invariant so result matches reference up to fp rounding).
// Edge chunks of 64 staged (src, p[4]) to LDS; 16-lane groups process 4 edges in
// parallel, unrolled x2 (8 edges in flight). LDS p is zero-padded past dg, so cnt
// rounds up to a multiple of 8 with no predication.
__global__ __launch_bounds__(256) void k_gat1(
    const unsigned short* __restrict__ xW, const float* __restrict__ es, const float* __restrict__ ed,
    const int* __restrict__ offs, const int* __restrict__ deg, const int* __restrict__ csr,
    const float* __restrict__ bias, unsigned short* __restrict__ out) {
    __shared__ float ps[4][256];
    __shared__ int sbuf[4][64];
    const int wv = threadIdx.x >> 6;
    const int lane = threadIdx.x & 63;
    const int n = blockIdx.x * 4 + wv;
    if (n >= N_NODES) return;
    const int off = offs[n];
    const int dg = deg[n];
    const float4 edv = *(const float4*)&ed[n * 4];
    const int t = lane & 15, grp = lane >> 4, hq = t >> 2;

    float acc[16];
#pragma unroll
    for (int k = 0; k < 16; ++k) acc[k] = 0.f;
    float d0 = 0.f, d1 = 0.f, d2 = 0.f, d3 = 0.f;

    for (int base = 0; base < dg; base += 64) {
        const int idx = base + lane;
        int s_l = 0;
        float p0 = 0.f, p1 = 0.f, p2 = 0.f, p3 = 0.f;
        if (idx < dg) {
            s_l = csr[off + idx];
            const float4 ev = *(const float4*)&es[s_l * 4];
            p0 = __expf(lrelu(ev.x + edv.x));
            p1 = __expf(lrelu(ev.y + edv.y));
            p2 = __expf(lrelu(ev.z + edv.z));
            p3 = __expf(lrelu(ev.w + edv.w));
        }
        d0 += p0; d1 += p1; d2 += p2; d3 += p3;
        *(float4*)&ps[wv][lane * 4] = make_float4(p0, p1, p2, p3);
        sbuf[wv][lane] = s_l;
        const int cnt = min(64, dg - base);
        const int cntR = (cnt + 7) & ~7;
        for (int j4 = 0; j4 < cntR; j4 += 8) {
            const int ja = j4 + grp;
            const int jb = ja + 4;
            const float pa = ps[wv][ja * 4 + hq];
            const float pb = ps[wv][jb * 4 + hq];
            const int sa = sbuf[wv][ja];
            const int sb = sbuf[wv][jb];
            const uint4 a0 = *(const uint4*)&xW[(size_t)sa * 256 + t * 16];
            const uint4 a1 = *(const uint4*)&xW[(size_t)sa * 256 + t * 16 + 8];
            const uint4 b0 = *(const uint4*)&xW[(size_t)sb * 256 + t * 16];
            const uint4 b1 = *(const uint4*)&xW[(size_t)sb * 256 + t * 16 + 8];
            acc[0]  = fmaf(pa, blo(a0.x), acc[0]);
            acc[1]  = fmaf(pa, bhi(a0.x), acc[1]);
            acc[2]  = fmaf(pa, blo(a0.y), acc[2]);
            acc[3]  = fmaf(pa, bhi(a0.y), acc[3]);
            acc[4]  = fmaf(pa, blo(a0.z), acc[4]);
            acc[5]  = fmaf(pa, bhi(a0.z), acc[5]);
            acc[6]  = fmaf(pa, blo(a0.w), acc[6]);
            acc[7]  = fmaf(pa, bhi(a0.w), acc[7]);
            acc[8]  = fmaf(pa, blo(a1.x), acc[8]);
            acc[9]  = fmaf(pa, bhi(a1.x), acc[9]);
            acc[10] = fmaf(pa, blo(a1.y), acc[10]);
            acc[11] = fmaf(pa, bhi(a1.y), acc[11]);
            acc[12] = fmaf(pa, blo(a1.z), acc[12]);
            acc[13] = fmaf(pa, bhi(a1.z), acc[13]);
            acc[14] = fmaf(pa, blo(a1.w), acc[14]);
            acc[15] = fmaf(pa, bhi(a1.w), acc[15]);
            acc[0]  = fmaf(pb, blo(b0.x), acc[0]);
            acc[1]  = fmaf(pb, bhi(b0.x), acc[1]);
            acc[2]  = fmaf(pb, blo(b0.y), acc[2]);
            acc[3]  = fmaf(pb, bhi(b0.y), acc[3]);
            acc[4]  = fmaf(pb, blo(b0.z), acc[4]);
            acc[5]  = fmaf(pb, bhi(b0.z), acc[5]);
            acc[6]  = fmaf(pb, blo(b0.w), acc[6]);
            acc[7]  = fmaf(pb, bhi(b0.w), acc[7]);
            acc[8]  = fmaf(pb, blo(b1.x), acc[8]);
            acc[9]  = fmaf(pb, bhi(b1.x), acc[9]);
            acc[10] = fmaf(pb, blo(b1.y), acc[10]);
            acc[11] = fmaf(pb, bhi(b1.y), acc[11]);
            acc[12] = fmaf(pb, blo(b1.z), acc[12]);
            acc[13] = fmaf(pb, bhi(b1.z), acc[13]);
            acc[14] = fmaf(pb, blo(b1.w), acc[14]);
            acc[15] = fmaf(pb, bhi(b1.w), acc[15]);
        }
    }
    // combine the 4 groups' partial sums (lanes g*16+t share the same cols)
#pragma unroll
    for (int k = 0; k < 16; ++k) {
        acc[k] += __shfl_xor(acc[k], 16);
        acc[k] += __shfl_xor(acc[k], 32);
    }
    for (int o = 1; o < 64; o <<= 1) {
        d0 += __shfl_xor(d0, o);
        d1 += __shfl_xor(d1, o);
        d2 += __shfl_xor(d2, o);
        d3 += __shfl_xor(d3, o);
    }
    if (grp == 0) {
        const float dsel = hq == 0 ? d0 : hq == 1 ? d1 : hq == 2 ? d2 : d3;
        const float inv = 1.0f / fmaxf(dsel, 1e-16f);
#pragma unroll
        for (int k4 = 0; k4 < 16; k4 += 4) {
            const int c = t * 16 + k4;
            const float4 bv = *(const float4*)&bias[c];
            ushort4 o4;
            o4.x = f2b(fmaxf(fmaf(acc[k4 + 0], inv, bv.x), 0.f));
            o4.y = f2b(fmaxf(fmaf(acc[k4 + 1], inv, bv.y), 0.f));
            o4.z = f2b(fmaxf(fmaf(acc[k4 + 2], inv, bv.z), 0.f));
            o4.w = f2b(fmaxf(fmaf(acc[k4 + 3], inv, bv.w), 0.f));
            *(ushort4*)&out[(size_t)n * 256 + c] = o4;
        }
    }
}

// ---------------- GAT layers 2-4: H=1, F=64, + bias + BN + relu (+ residual) ----------------
// Single pass, 8-lane groups, 8 edges in parallel, unrolled x2 (16 in flight).
template <bool RES>
__global__ __launch_bounds__(256) void k_gatL(
    const unsigned short* __restrict__ xW, const float* __restrict__ es, const float* __restrict__ ed,
    const int* __restrict__ offs, const int* __restrict__ deg, const int* __restrict__ csr,
    const float* __restrict__ bias, const float* __restrict__ gam, const float* __restrict__ bet,
    float* __restrict__ h, unsigned short* __restrict__ hb) {
    __shared__ float ps[4][64];
    __shared__ int sbuf[4][64];
    const int wv = threadIdx.x >> 6;
    const int lane = threadIdx.x & 63;
    const int n = blockIdx.x * 4 + wv;
    if (n >= N_NODES) return;
    const int off = offs[n];
    const int dg = deg[n];
    const float edn = ed[n];
    const int t = lane & 7, grp = lane >> 3;

    float acc[8];
#pragma unroll
    for (int k = 0; k < 8; ++k) acc[k] = 0.f;
    float dsum = 0.f;

    for (int base = 0; base < dg; base += 64) {
        const int idx = base + lane;
        int s_l = 0;
        float p_l = 0.f;
        if (idx < dg) {
            s_l = csr[off + idx];
            p_l = __expf(lrelu(es[s_l] + edn));
        }
        dsum += p_l;
        ps[wv][lane] = p_l;
        sbuf[wv][lane] = s_l;
        const int cnt = min(64, dg - base);
        const int cntR = (cnt + 15) & ~15;
        for (int j8 = 0; j8 < cntR; j8 += 16) {
            const int ja = j8 + grp;
            const int jb = ja + 8;
            const float pa = ps[wv][ja];
            const float pb = ps[wv][jb];
            const int sa = sbuf[wv][ja];
            const int sb = sbuf[wv][jb];
            const uint4 a = *(const uint4*)&xW[(size_t)sa * 64 + t * 8];
            const uint4 b = *(const uint4*)&xW[(size_t)sb * 64 + t * 8];
            acc[0] = fmaf(pa, blo(a.x), acc[0]);
            acc[1] = fmaf(pa, bhi(a.x), acc[1]);
            acc[2] = fmaf(pa, blo(a.y), acc[2]);
            acc[3] = fmaf(pa, bhi(a.y), acc[3]);
            acc[4] = fmaf(pa, blo(a.z), acc[4]);
            acc[5] = fmaf(pa, bhi(a.z), acc[5]);
            acc[6] = fmaf(pa, blo(a.w), acc[6]);
            acc[7] = fmaf(pa, bhi(a.w), acc[7]);
            acc[0] = fmaf(pb, blo(b.x), acc[0]);
            acc[1] = fmaf(pb, bhi(b.x), acc[1]);
            acc[2] = fmaf(pb, blo(b.y), acc[2]);
            acc[3] = fmaf(pb, bhi(b.y), acc[3]);
            acc[4] = fmaf(pb, blo(b.z), acc[4]);
            acc[5] = fmaf(pb, bhi(b.z), acc[5]);
            acc[6] = fmaf(pb, blo(b.w), acc[6]);
            acc[7] = fmaf(pb, bhi(b.w), acc[7]);
        }
    }
#pragma unroll
    for (int k = 0; k < 8; ++k) {
        acc[k] += __shfl_xor(acc[k], 8);
        acc[k] += __shfl_xor(acc[k], 16);
        acc[k] += __shfl_xor(acc[k], 32);
    }
    for (int o = 1; o < 64; o <<= 1) dsum += __shfl_xor(dsum, o);

    if (grp == 0) {
        const float inv = 1.0f / fmaxf(dsum, 1e-16f);
        const int c0 = t * 8;
        float hn[8];
#pragma unroll
        for (int k = 0; k < 8; ++k) {
            const int c = c0 + k;
            const float y = fmaf(acc[k], inv, bias[c]);
            const float z = fmaxf(fmaf(gam[c] * y, BN_RSQ, bet[c]), 0.f);
            hn[k] = RES ? h[(size_t)n * 64 + c] + z : z;
        }
        *(float4*)&h[(size_t)n * 64 + c0] = make_float4(hn[0], hn[1], hn[2], hn[3]);
        *(float4*)&h[(size_t)n * 64 + c0 + 4] = make_float4(hn[4], hn[5], hn[6], hn[7]);
        ushort4 u0, u1;
        u0.x = f2b(hn[0]); u0.y = f2b(hn[1]); u0.z = f2b(hn[2]); u0.w = f2b(hn[3]);
        u1.x = f2b(hn[4]); u1.y = f2b(hn[5]); u1.z = f2b(hn[6]); u1.w = f2b(hn[7]);
        *(ushort4*)&hb[(size_t)n * 64 + c0] = u0;
        *(ushort4*)&hb[(size_t)n * 64 + c0 + 4] = u1;
    }
}

// ---------------- mean pool: one block per graph, contiguous node range, no atomics ----------------
__global__ __launch_bounds__(256) void k_pool2(const float* __restrict__ h,
                                               const int* __restrict__ bounds,
                                               float* __restrict__ hp) {
    __shared__ float part[4][64];
    const int g = blockIdx.x;
    const int lane = threadIdx.x & 63;
    const int wid = threadIdx.x >> 6;
    const int s = bounds[g], e = bounds[g + 1];
    float acc = 0.f;
    for (int n = s + wid; n < e; n += 4) acc += h[n * 64 + lane];
    part[wid][lane] = acc;
    __syncthreads();
    if (wid == 0) {
        float v = part[0][lane] + part[1][lane] + part[2][lane] + part[3][lane];
        hp[g * 64 + lane] = v / fmaxf((float)(e - s), 1.0f);
    }
}

// ---------------- MLP head, single block (hp already mean-pooled) ----------------
__global__ __launch_bounds__(256) void k_head(const float* __restrict__ hpg,
                                              const float* __restrict__ Wh1,
                                              const float* __restrict__ bh1,
                                              const float* __restrict__ Wh2,
                                              const float* __restrict__ bh2,
                                              float* __restrict__ out) {
    __shared__ float hp[64 * 64];
    __shared__ float t1[64 * 128];
    const int tid = threadIdx.x;
    for (int i = tid; i < 64 * 64; i += 256) hp[i] = hpg[i];
    __syncthreads();
    for (int i = tid; i < 64 * 128; i += 256) {
        int g = i >> 7, j = i & 127;
        float s = bh1[j];
        for (int k = 0; k < 64; ++k) s = fmaf(hp[g * 64 + k], Wh1[k * 128 + j], s);
        t1[i] = fmaxf(s, 0.f);
    }
    __syncthreads();
    for (int i = tid; i < 640; i += 256) {
        int g = i / 10, j = i - g * 10;
        float s = bh2[j];
        for (int k = 0; k < 128; ++k) s = fmaf(t1[g * 128 + k], Wh2[k * 10 + j], s);
        out[i] = s;
    }
}

extern "C" void kernel_launch(void* const* d_in, const int* in_sizes, int n_in,
                              void* d_out, int out_size, void* d_ws, size_t ws_size,
                              hipStream_t stream) {
    const float* x = (const float*)d_in[1];
    const int* ei = (const int*)d_in[2];
    const int* batch = (const int*)d_in[3];
    const float* W1 = (const float*)d_in[4];
    const float* a_src1 = (const float*)d_in[5];
    const float* a_dst1 = (const float*)d_in[6];
    const float* b1 = (const float*)d_in[7];
    const float* W2 = (const float*)d_in[8];
    const float* a_src2 = (const float*)d_in[9];
    const float* a_dst2 = (const float*)d_in[10];
    const float* b2 = (const float*)d_in[11];
    const float* g2 = (const float*)d_in[12];
    const float* be2 = (const float*)d_in[13];
    const float* W3 = (const float*)d_in[14];
    const float* a_src3 = (const float*)d_in[15];
    const float* a_dst3 = (const float*)d_in[16];
    const float* b3 = (const float*)d_in[17];
    const float* g3 = (const float*)d_in[18];
    const float* be3 = (const float*)d_in[19];
    const float* W4 = (const float*)d_in[20];
    const float* a_src4 = (const float*)d_in[21];
    const float* a_dst4 = (const float*)d_in[22];
    const float* b4 = (const float*)d_in[23];
    const float* g4 = (const float*)d_in[24];
    const float* be4 = (const float*)d_in[25];
    const float* Wh1 = (const float*)d_in[26];
    const float* bh1 = (const float*)d_in[27];
    const float* Wh2 = (const float*)d_in[28];
    const float* bh2 = (const float*)d_in[29];
    float* out = (float*)d_out;

    // workspace layout
    char* p = (char*)d_ws;
    auto alloc = [&](size_t bytes) {
        void* r = (void*)p;
        p += (bytes + 255) & ~(size_t)255;
        return r;
    };
    unsigned short* bufA = (unsigned short*)alloc((size_t)N_NODES * 256 * 2);  // xW bf16 per layer
    unsigned short* x1b = (unsigned short*)alloc((size_t)N_NODES * 256 * 2);   // x1 bf16
    float* h = (float*)alloc((size_t)N_NODES * 64 * 4);                        // h fp32
    unsigned short* hb = (unsigned short*)alloc((size_t)N_NODES * 64 * 2);     // h bf16
    float* es1 = (float*)alloc((size_t)N_NODES * 4 * 4);
    float* ed1 = (float*)alloc((size_t)N_NODES * 4 * 4);
    float* esL = (float*)alloc((size_t)N_NODES * 4);
    float* edL = (float*)alloc((size_t)N_NODES * 4);
    int* offs = (int*)alloc((size_t)N_NODES * 4);
    int* csr = (int*)alloc((size_t)N_EDGES * 4);
    int* bounds = (int*)alloc((size_t)(N_GRAPHS + 1) * 4);
    float* hpool = (float*)alloc((size_t)N_GRAPHS * 64 * 4);
    unsigned short* Wt1 = (unsigned short*)alloc((size_t)128 * 256 * 2);
    unsigned short* Wt2 = (unsigned short*)alloc((size_t)256 * 64 * 2);
    unsigned short* Wt3 = (unsigned short*)alloc((size_t)64 * 64 * 2);
    unsigned short* Wt4 = (unsigned short*)alloc((size_t)64 * 64 * 2);
    char* z0 = p;  // everything below gets zeroed each call
    int* deg = (int*)alloc((size_t)N_NODES * 4);
    int* cur = (int*)alloc((size_t)N_NODES * 4);
    int* total = (int*)alloc(256);
    size_t zbytes = (size_t)(p - z0);
    hipMemsetAsync(z0, 0, zbytes, stream);

    const int edgeBlocks = (N_EDGES + 255) / 256;
    const int nodeBlocks = (N_NODES + 255) / 256;
    const int mgemmBlocks = (N_NODES + 63) / 64;
    const int gatBlocks = (N_NODES + 3) / 4;  // 4 node-waves per block

    // weight prep (bf16 transpose)
    k_prepw<<<(128 * 256 + 255) / 256, 256, 0, stream>>>(W1, Wt1, 128, 256);
    k_prepw<<<(256 * 64 + 255) / 256, 256, 0, stream>>>(W2, Wt2, 256, 64);
    k_prepw<<<(64 * 64 + 255) / 256, 256, 0, stream>>>(W3, Wt3, 64, 64);
    k_prepw<<<(64 * 64 + 255) / 256, 256, 0, stream>>>(W4, Wt4, 64, 64);

    // CSR build + graph bounds
    k_deg<<<edgeBlocks, 256, 0, stream>>>(ei, deg);
    k_offs<<<nodeBlocks, 256, 0, stream>>>(deg, offs, total);
    k_fill<<<edgeBlocks, 256, 0, stream>>>(ei, offs, cur, csr);
    k_bounds<<<1, 128, 0, stream>>>(batch, bounds);

    // layer 1: GAT(128 -> 4x64, concat) + relu  (dots fused into GEMM epilogue)
    k_mgemm<128, 256, 4, true><<<mgemmBlocks, 256, 0, stream>>>(x, Wt1, a_src1, a_dst1,
                                                                bufA, es1, ed1, N_NODES);
    k_gat1<<<gatBlocks, 256, 0, stream>>>(bufA, es1, ed1, offs, deg, csr, b1, x1b);

    // layer 2: GAT(256 -> 64) + BN + relu
    k_mgemm<256, 64, 1, false><<<mgemmBlocks, 256, 0, stream>>>(x1b, Wt2, a_src2, a_dst2,
                                                                bufA, esL, edL, N_NODES);
    k_gatL<false><<<gatBlocks, 256, 0, stream>>>(bufA, esL, edL, offs, deg, csr, b2, g2, be2, h, hb);

    // layer 3: residual GAT(64 -> 64) + BN + relu
    k_mgemm<64, 64, 1, false><<<mgemmBlocks, 256, 0, stream>>>(hb, Wt3, a_src3, a_dst3,
                                                               bufA, esL, edL, N_NODES);
    k_gatL<true><<<gatBlocks, 256, 0, stream>>>(bufA, esL, edL, offs, deg, csr, b3, g3, be3, h, hb);

    // layer 4: residual GAT(64 -> 64) + BN + relu
    k_mgemm<64, 64, 1, false><<<mgemmBlocks, 256, 0, stream>>>(hb, Wt4, a_src4, a_dst4,
                                                               bufA, esL, edL, N_NODES);
    k_gatL<true><<<gatBlocks, 256, 0, stream>>>(bufA, esL, edL, offs, deg, csr, b4, g4, be4, h, hb);

    // pool + head (batch sorted -> contiguous ranges, no atomics)
    k_pool2<<<N_GRAPHS, 256, 0, stream>>>(h, bounds, hpool);
    k_head<<<1, 256, 0, stream>>>(hpool, Wh1, bh1, Wh2, bh2, out);
}